// Round 1
// baseline (1567.192 us; speedup 1.0000x reference)
//
#include <hip/hip_runtime.h>
#include <hip/hip_bf16.h>
#include <math.h>

// Problem constants
#define BATCH 16
#define CDIM  128
#define JDIM  16
#define LDIM  16
#define NCODE 16384
#define PLANE 256            // J*L
#define ELEMS 524288         // B*C*J*L
#define NTOT  5456           // 16+64+256+1024+4096
// loss coeff: 1.25 / (5 * 524288) == 2^-21
#define LOSS_COEF 4.76837158203125e-7f

// ---------------------------------------------------------------------------
// init: f_rest = f, f_hat(out) = 0, counts = 0, loss = 0
__global__ void k_init(const float* __restrict__ f, float* __restrict__ f_rest,
                       float* __restrict__ f_hat, float* __restrict__ counts,
                       float* __restrict__ loss_acc) {
    int i = blockIdx.x * 256 + threadIdx.x;
    if (i < ELEMS) { f_rest[i] = f[i]; f_hat[i] = 0.f; }
    if (i < NCODE) counts[i] = 0.f;
    if (i == 0) loss_acc[0] = 0.f;
}

// ---------------------------------------------------------------------------
// e_sq[k] = sum_c emb[k][c]^2
__global__ void k_esq(const float* __restrict__ emb, float* __restrict__ esq) {
    int k = blockIdx.x * 256 + threadIdx.x;
    if (k >= NCODE) return;
    const float4* e = reinterpret_cast<const float4*>(emb + (size_t)k * CDIM);
    float s = 0.f;
    #pragma unroll
    for (int q = 0; q < 32; ++q) {
        float4 v = e[q];
        s += v.x * v.x + v.y * v.y + v.z * v.z + v.w * v.w;
    }
    esq[k] = s;
}

// ---------------------------------------------------------------------------
// bicubic interpolation matrices (align_corners=False, a=-0.75), double math
__device__ double cubic_d(double x) {
    const double a = -0.75;
    double ax = fabs(x);
    if (ax <= 1.0) return (a + 2.0) * ax * ax * ax - (a + 3.0) * ax * ax + 1.0;
    if (ax < 2.0)  return a * ax * ax * ax - 5.0 * a * ax * ax + 8.0 * a * ax - 4.0 * a;
    return 0.0;
}
__global__ void k_wmat(float* __restrict__ wm) {
    int t = threadIdx.x;          // 64 threads = 4 scales x 16 rows
    if (t >= 64) return;
    int sIdx = t >> 4;            // 0..3 -> S = 1,2,4,8
    int S = 1 << sIdx;
    int j = t & 15;
    const int offs[4] = {0, 16, 48, 112};
    int off = offs[sIdx];
    double row[8];
    for (int s = 0; s < 8; ++s) row[s] = 0.0;
    double scale = (double)S / 16.0;
    double x = (j + 0.5) * scale - 0.5;
    double x0 = floor(x);
    double tt = x - x0;
    for (int k = 0; k < 4; ++k) {
        int idx = (int)x0 - 1 + k;
        idx = idx < 0 ? 0 : (idx > S - 1 ? S - 1 : idx);
        row[idx] += cubic_d(tt + 1.0 - k);
    }
    for (int s = 0; s < S; ++s) wm[off + j * S + s] = (float)row[s];
}

// ---------------------------------------------------------------------------
// pack: r[n][c] = blockmean of f_rest ; thread-per-output (S=4,8,16)
__global__ void k_pack(const float* __restrict__ fr, float* __restrict__ rOut,
                       int S, int lgS) {
    int id = blockIdx.x * 256 + threadIdx.x;
    int total = 16 * S * S * 128;
    if (id >= total) return;
    int c = id & 127, n = id >> 7;
    int mask = S - 1;
    int tt = n & mask, ss = (n >> lgS) & mask, b = n >> (2 * lgS);
    int bs = 16 >> lgS;
    const float* base = fr + (size_t)(b * 128 + c) * 256 + (ss * bs) * 16 + tt * bs;
    float acc = 0.f;
    for (int jj = 0; jj < bs; ++jj)
        for (int ll = 0; ll < bs; ++ll)
            acc += base[jj * 16 + ll];
    rOut[id] = acc / (float)(bs * bs);
}

// wave-per-output variant for S=1,2 (large reduction windows)
__global__ void k_pack_wave(const float* __restrict__ fr, float* __restrict__ rOut,
                            int S, int lgS) {
    int gid = blockIdx.x * 256 + threadIdx.x;
    int wid = gid >> 6;
    int lane = threadIdx.x & 63;
    int total = 16 * S * S * 128;
    if (wid >= total) return;
    int c = wid & 127, n = wid >> 7;
    int mask = S - 1;
    int tt = n & mask, ss = (n >> lgS) & mask, b = n >> (2 * lgS);
    int lgbs = 4 - lgS;
    int bs = 1 << lgbs;
    int cnt = bs * bs;
    const float* base = fr + (size_t)(b * 128 + c) * 256 + (ss * bs) * 16 + tt * bs;
    float acc = 0.f;
    for (int e = lane; e < cnt; e += 64) {
        int jj = e >> lgbs, ll = e & (bs - 1);
        acc += base[jj * 16 + ll];
    }
    #pragma unroll
    for (int off = 32; off; off >>= 1) acc += __shfl_down(acc, off);
    if (lane == 0) rOut[wid] = acc / (float)cnt;
}

// ---------------------------------------------------------------------------
// argmin over codes: score = esq[k] - 2 * dot(r[n], emb[k])
// block: 128 threads, row tile MT=32, code tile KT=64, micro 4x4, K-split grid.y
#define CPAD 132
__global__ __launch_bounds__(128)
void k_argmin(const float* __restrict__ r, const float* __restrict__ emb,
              const float* __restrict__ esq, int N, int kPerSplit,
              float* __restrict__ pval, int* __restrict__ pidx) {
    __shared__ float rT[32][CPAD];
    __shared__ float eT[64][CPAD];
    const int t = threadIdx.x;
    const int rowBase = blockIdx.x * 32;
    const int KS = gridDim.y;
    const int k0beg = blockIdx.y * kPerSplit;

    #pragma unroll
    for (int p = 0; p < 8; ++p) {          // stage 32x128 rows of r
        int v = t + p * 128;
        int row = v >> 5, cq = v & 31;
        float4 val = make_float4(0.f, 0.f, 0.f, 0.f);
        if (rowBase + row < N)
            val = reinterpret_cast<const float4*>(r + (size_t)(rowBase + row) * CDIM)[cq];
        *reinterpret_cast<float4*>(&rT[row][cq * 4]) = val;
    }

    const int rg = t & 7;     // row group (8)  -> rows rg + 8j
    const int cg = t >> 3;    // code group (16)-> codes cg + 16i

    float minv[4] = {3.4e38f, 3.4e38f, 3.4e38f, 3.4e38f};
    int   mini[4] = {0, 0, 0, 0};

    for (int k0 = k0beg; k0 < k0beg + kPerSplit; k0 += 64) {
        __syncthreads();
        #pragma unroll
        for (int p = 0; p < 16; ++p) {     // stage 64x128 codes
            int v = t + p * 128;
            int kr = v >> 5, cq = v & 31;
            *reinterpret_cast<float4*>(&eT[kr][cq * 4]) =
                reinterpret_cast<const float4*>(emb + (size_t)(k0 + kr) * CDIM)[cq];
        }
        __syncthreads();

        float acc[4][4];
        #pragma unroll
        for (int j = 0; j < 4; ++j)
            #pragma unroll
            for (int i = 0; i < 4; ++i) acc[j][i] = 0.f;

        #pragma unroll 8
        for (int cq = 0; cq < 32; ++cq) {
            float4 ev[4], rv[4];
            #pragma unroll
            for (int i = 0; i < 4; ++i)
                ev[i] = *reinterpret_cast<const float4*>(&eT[cg + 16 * i][cq * 4]);
            #pragma unroll
            for (int j = 0; j < 4; ++j)
                rv[j] = *reinterpret_cast<const float4*>(&rT[rg + 8 * j][cq * 4]);
            #pragma unroll
            for (int j = 0; j < 4; ++j)
                #pragma unroll
                for (int i = 0; i < 4; ++i)
                    acc[j][i] += rv[j].x * ev[i].x + rv[j].y * ev[i].y +
                                 rv[j].z * ev[i].z + rv[j].w * ev[i].w;
        }

        #pragma unroll
        for (int i = 0; i < 4; ++i) {
            int code = k0 + cg + 16 * i;
            float es = esq[code];
            #pragma unroll
            for (int j = 0; j < 4; ++j) {
                float sc = es - 2.f * acc[j][i];
                if (sc < minv[j]) { minv[j] = sc; mini[j] = code; }
            }
        }
    }

    __syncthreads();
    float (*redV)[16] = reinterpret_cast<float(*)[16]>(&rT[0][0]);
    int   (*redI)[16] = reinterpret_cast<int(*)[16]>(&eT[0][0]);
    #pragma unroll
    for (int j = 0; j < 4; ++j) {
        redV[rg + 8 * j][cg] = minv[j];
        redI[rg + 8 * j][cg] = mini[j];
    }
    __syncthreads();
    if (t < 32) {
        float bv = redV[t][0]; int bi = redI[t][0];
        #pragma unroll
        for (int g = 1; g < 16; ++g) {
            float v = redV[t][g];
            if (v < bv) { bv = v; bi = redI[t][g]; }
        }
        int row = rowBase + t;
        if (row < N) {
            pval[(size_t)row * KS + blockIdx.y] = bv;
            pidx[(size_t)row * KS + blockIdx.y] = bi;
        }
    }
}

__global__ void k_argmin_reduce(const float* __restrict__ pval,
                                const int* __restrict__ pidx,
                                int N, int KS, int* __restrict__ idx_out) {
    int row = blockIdx.x * 256 + threadIdx.x;
    if (row >= N) return;
    float bv = pval[(size_t)row * KS];
    int bi = pidx[(size_t)row * KS];
    for (int ks = 1; ks < KS; ++ks) {
        float v = pval[(size_t)row * KS + ks];
        if (v < bv) { bv = v; bi = pidx[(size_t)row * KS + ks]; }
    }
    idx_out[row] = bi;
}

// ---------------------------------------------------------------------------
// bicubic upsample of gathered codes: block = one (b,c) 16x16 plane
__global__ void k_upsample(const float* __restrict__ emb, const int* __restrict__ idx,
                           const float* __restrict__ wm, int S, float* __restrict__ h_up) {
    const int bc = blockIdx.x;
    const int b = bc >> 7, c = bc & 127;
    const int t = threadIdx.x;
    const int j = t >> 4, l = t & 15;
    float acc = 0.f;
    for (int s = 0; s < S; ++s) {
        float wjv = wm[j * S + s];
        for (int tt = 0; tt < S; ++tt) {
            float wlv = wm[l * S + tt];
            int n = (b * S + s) * S + tt;
            acc += wjv * wlv * emb[(size_t)idx[n] * CDIM + c];
        }
    }
    h_up[(size_t)bc * 256 + t] = acc;
}

// scale 4: plain gather-transpose
__global__ void k_gather16(const float* __restrict__ emb, const int* __restrict__ idx,
                           float* __restrict__ h_up) {
    int id = blockIdx.x * 256 + threadIdx.x;
    int l = id & 15, j = (id >> 4) & 15, c = (id >> 8) & 127, b = id >> 15;
    int n = (b * 16 + j) * 16 + l;
    h_up[id] = emb[(size_t)idx[n] * CDIM + c];
}

// ---------------------------------------------------------------------------
// conv3x3 (SAME, zero pad) + 0.5 residual mix + f_hat/f_rest update + loss
// grid = 16 b x 16 co-groups (8 co each); 256 thr = 8 co x 32 (2x4) tiles
__global__ __launch_bounds__(256)
void k_conv(const float* __restrict__ h_up, const float* __restrict__ w,
            const float* __restrict__ bias, const float* __restrict__ f_in,
            float* __restrict__ f_hat, float* __restrict__ f_rest,
            float* __restrict__ loss_acc) {
    __shared__ float tile[8][256];
    __shared__ float wl[576];          // 8 co x 8 ci x 9
    __shared__ float wsum[4];
    const int b   = blockIdx.x >> 4;
    const int co0 = (blockIdx.x & 15) * 8;
    const int t = threadIdx.x;
    const int col = t >> 5;            // co_local 0..7
    const int tid5 = t & 31;
    const int j0 = (tid5 >> 2) * 2;
    const int l0 = (tid5 & 3) * 4;
    const int co = co0 + col;
    const float* hb = h_up + (size_t)b * 32768;
    float acc[2][4] = {{0.f,0.f,0.f,0.f},{0.f,0.f,0.f,0.f}};

    for (int ci0 = 0; ci0 < 128; ci0 += 8) {
        __syncthreads();
        #pragma unroll
        for (int p = 0; p < 8; ++p) tile[p][t] = hb[(ci0 + p) * 256 + t];
        for (int i = t; i < 576; i += 256) {
            int cl = i / 72, rem = i % 72;
            int p = rem / 9, q = rem % 9;
            wl[i] = w[((size_t)(co0 + cl) * 128 + (ci0 + p)) * 9 + q];
        }
        __syncthreads();
        #pragma unroll
        for (int p = 0; p < 8; ++p) {
            float in[4][6];
            #pragma unroll
            for (int rr = 0; rr < 4; ++rr) {
                int jj = j0 - 1 + rr;
                #pragma unroll
                for (int cc = 0; cc < 6; ++cc) {
                    int ll = l0 - 1 + cc;
                    in[rr][cc] = (jj >= 0 && jj < 16 && ll >= 0 && ll < 16)
                                   ? tile[p][jj * 16 + ll] : 0.f;
                }
            }
            const float* wp = &wl[(col * 8 + p) * 9];
            #pragma unroll
            for (int dj = 0; dj < 3; ++dj)
                #pragma unroll
                for (int dl = 0; dl < 3; ++dl) {
                    float wv = wp[dj * 3 + dl];
                    #pragma unroll
                    for (int rr = 0; rr < 2; ++rr)
                        #pragma unroll
                        for (int cc = 0; cc < 4; ++cc)
                            acc[rr][cc] += wv * in[dj + rr][dl + cc];
                }
        }
    }

    float bsv = bias[co];
    float s = 0.f;
    #pragma unroll
    for (int rr = 0; rr < 2; ++rr) {
        #pragma unroll
        for (int cc = 0; cc < 4; ++cc) {
            int j = j0 + rr, l = l0 + cc;
            size_t gi = (size_t)(b * 128 + co) * 256 + j * 16 + l;
            float hv = h_up[gi];
            float outv = 0.5f * hv + 0.5f * (acc[rr][cc] + bsv);
            float fh = f_hat[gi] + outv;
            f_hat[gi] = fh;
            f_rest[gi] -= outv;
            float d = fh - f_in[gi];
            s += d * d;
        }
    }
    #pragma unroll
    for (int off = 32; off; off >>= 1) s += __shfl_down(s, off);
    if ((t & 63) == 0) wsum[t >> 6] = s;
    __syncthreads();
    if (t == 0)
        atomicAdd(loss_acc, (wsum[0] + wsum[1] + wsum[2] + wsum[3]) * LOSS_COEF);
}

// ---------------------------------------------------------------------------
__global__ void k_scatter(const int* __restrict__ idxb, float* __restrict__ counts) {
    int i = blockIdx.x * 256 + threadIdx.x;
    if (i < NTOT) atomicAdd(&counts[idxb[i]], 1.0f);
}

__global__ void k_final(const float* __restrict__ counts,
                        const float* __restrict__ loss_acc, float* __restrict__ out) {
    __shared__ float ws4[4];
    int t = threadIdx.x;
    float s = 0.f;
    for (int k = t; k < NCODE; k += 256) {
        float p = counts[k] * (1.0f / (float)NTOT);
        s += p * logf(p + 1e-10f);
    }
    #pragma unroll
    for (int off = 32; off; off >>= 1) s += __shfl_down(s, off);
    if ((t & 63) == 0) ws4[t >> 6] = s;
    __syncthreads();
    if (t == 0) {
        out[ELEMS]     = loss_acc[0];
        out[ELEMS + 1] = expf(-(ws4[0] + ws4[1] + ws4[2] + ws4[3]));
    }
}

// ---------------------------------------------------------------------------
extern "C" void kernel_launch(void* const* d_in, const int* in_sizes, int n_in,
                              void* d_out, int out_size, void* d_ws, size_t ws_size,
                              hipStream_t stream) {
    const float* f     = (const float*)d_in[0];
    const float* emb   = (const float*)d_in[1];
    const float* phi_w = (const float*)d_in[2];
    const float* phi_b = (const float*)d_in[3];
    float* out = (float*)d_out;

    float* wsf    = (float*)d_ws;
    float* f_rest = wsf;                    // 524288
    float* h_up   = wsf + 524288;           // 524288
    float* rbuf   = wsf + 1048576;          // 524288
    float* esq    = wsf + 1572864;          // 16384
    float* wmat   = wsf + 1589248;          // 256
    float* counts = wsf + 1589504;          // 16384
    float* lossA  = wsf + 1605888;          // 64 (padded)
    float* pval   = wsf + 1605952;          // 32768
    int*   pidx   = (int*)(wsf + 1638720);  // 32768
    int*   idxb   = (int*)(wsf + 1671488);  // 5456

    k_init<<<2048, 256, 0, stream>>>(f, f_rest, out, counts, lossA);
    k_esq<<<64, 256, 0, stream>>>(emb, esq);
    k_wmat<<<1, 64, 0, stream>>>(wmat);

    const int Ss[5]     = {1, 2, 4, 8, 16};
    const int lgSs[5]   = {0, 1, 2, 3, 4};
    const int phiIdx[5] = {0, 1, 1, 2, 3};
    const int ksplit[5] = {256, 256, 64, 16, 4};
    const int wmOff[5]  = {0, 16, 48, 112, 0};
    int idxOff = 0;

    for (int si = 0; si < 5; ++si) {
        int S = Ss[si], lgS = lgSs[si];
        int N = 16 * S * S;
        int total = N * 128;

        if (S <= 2)
            k_pack_wave<<<(total * 64 + 255) / 256, 256, 0, stream>>>(f_rest, rbuf, S, lgS);
        else
            k_pack<<<(total + 255) / 256, 256, 0, stream>>>(f_rest, rbuf, S, lgS);

        int rb = (N + 31) / 32;
        int KS = ksplit[si];
        int kps = NCODE / KS;
        k_argmin<<<dim3(rb, KS), 128, 0, stream>>>(rbuf, emb, esq, N, kps, pval, pidx);
        k_argmin_reduce<<<(N + 255) / 256, 256, 0, stream>>>(pval, pidx, N, KS, idxb + idxOff);

        if (si < 4)
            k_upsample<<<2048, 256, 0, stream>>>(emb, idxb + idxOff, wmat + wmOff[si], S, h_up);
        else
            k_gather16<<<2048, 256, 0, stream>>>(emb, idxb + idxOff, h_up);

        int k = phiIdx[si];
        k_conv<<<256, 256, 0, stream>>>(h_up, phi_w + (size_t)k * 147456,
                                        phi_b + (size_t)k * 128, f, out, f_rest, lossA);
        idxOff += N;
    }

    k_scatter<<<(NTOT + 255) / 256, 256, 0, stream>>>(idxb, counts);
    k_final<<<1, 256, 0, stream>>>(counts, lossA, out);
}

// Round 2
// 931.831 us; speedup vs baseline: 1.6818x; 1.6818x over previous
//
#include <hip/hip_runtime.h>
#include <hip/hip_bf16.h>
#include <math.h>

// Problem constants
#define BATCH 16
#define CDIM  128
#define JDIM  16
#define LDIM  16
#define NCODE 16384
#define PLANE 256            // J*L
#define ELEMS 524288         // B*C*J*L
#define NTOT  5456           // 16+64+256+1024+4096
// loss coeff: 1.25 / (5 * 524288) == 2^-21
#define LOSS_COEF 4.76837158203125e-7f

typedef __attribute__((ext_vector_type(8))) short short8;
typedef __attribute__((ext_vector_type(4))) float float4v;
typedef unsigned short ushortT;

// ---------------------------------------------------------------------------
// init: f_rest = f, f_hat(out) = 0, counts = 0, loss = 0
__global__ void k_init(const float* __restrict__ f, float* __restrict__ f_rest,
                       float* __restrict__ f_hat, float* __restrict__ counts,
                       float* __restrict__ loss_acc) {
    int i = blockIdx.x * 256 + threadIdx.x;
    if (i < ELEMS) { f_rest[i] = f[i]; f_hat[i] = 0.f; }
    if (i < NCODE) counts[i] = 0.f;
    if (i == 0) loss_acc[0] = 0.f;
}

// ---------------------------------------------------------------------------
// e_sq[k] = sum_c emb[k][c]^2
__global__ void k_esq(const float* __restrict__ emb, float* __restrict__ esq) {
    int k = blockIdx.x * 256 + threadIdx.x;
    if (k >= NCODE) return;
    const float4* e = reinterpret_cast<const float4*>(emb + (size_t)k * CDIM);
    float s = 0.f;
    #pragma unroll
    for (int q = 0; q < 32; ++q) {
        float4 v = e[q];
        s += v.x * v.x + v.y * v.y + v.z * v.z + v.w * v.w;
    }
    esq[k] = s;
}

// ---------------------------------------------------------------------------
// emb -> split-bf16 extended rows: [hi(128) | lo(128)] per code
__global__ void k_embext(const float* __restrict__ emb, ushortT* __restrict__ ee) {
    int id = blockIdx.x * 256 + threadIdx.x;   // 16384*32
    if (id >= NCODE * 32) return;
    int row = id >> 5, c4 = id & 31;
    float4 v = reinterpret_cast<const float4*>(emb + (size_t)row * CDIM)[c4];
    ushortT hi[4], lo[4];
    float xs[4] = {v.x, v.y, v.z, v.w};
    #pragma unroll
    for (int i = 0; i < 4; ++i) {
        __hip_bfloat16 h = __float2bfloat16(xs[i]);
        hi[i] = *reinterpret_cast<ushortT*>(&h);
        float rem = xs[i] - __bfloat162float(h);
        __hip_bfloat16 l = __float2bfloat16(rem);
        lo[i] = *reinterpret_cast<ushortT*>(&l);
    }
    ushortT* base = ee + (size_t)row * 256;
    *reinterpret_cast<ushort4*>(base + c4 * 4)       = make_ushort4(hi[0], hi[1], hi[2], hi[3]);
    *reinterpret_cast<ushort4*>(base + 128 + c4 * 4) = make_ushort4(lo[0], lo[1], lo[2], lo[3]);
}

// r (fp32 [N][128]) -> split-bf16 [padN][hi(128)|lo(128)], zero pad rows
__global__ void k_rext(const float* __restrict__ r, ushortT* __restrict__ re,
                       int N, int padN) {
    int id = blockIdx.x * 256 + threadIdx.x;   // padN*32
    if (id >= padN * 32) return;
    int row = id >> 5, c4 = id & 31;
    ushortT hi[4], lo[4];
    if (row < N) {
        float4 v = reinterpret_cast<const float4*>(r + (size_t)row * CDIM)[c4];
        float xs[4] = {v.x, v.y, v.z, v.w};
        #pragma unroll
        for (int i = 0; i < 4; ++i) {
            __hip_bfloat16 h = __float2bfloat16(xs[i]);
            hi[i] = *reinterpret_cast<ushortT*>(&h);
            float rem = xs[i] - __bfloat162float(h);
            __hip_bfloat16 l = __float2bfloat16(rem);
            lo[i] = *reinterpret_cast<ushortT*>(&l);
        }
    } else {
        #pragma unroll
        for (int i = 0; i < 4; ++i) { hi[i] = 0; lo[i] = 0; }
    }
    ushortT* base = re + (size_t)row * 256;
    *reinterpret_cast<ushort4*>(base + c4 * 4)       = make_ushort4(hi[0], hi[1], hi[2], hi[3]);
    *reinterpret_cast<ushort4*>(base + 128 + c4 * 4) = make_ushort4(lo[0], lo[1], lo[2], lo[3]);
}

// ---------------------------------------------------------------------------
// bicubic interpolation matrices (align_corners=False, a=-0.75), double math
__device__ double cubic_d(double x) {
    const double a = -0.75;
    double ax = fabs(x);
    if (ax <= 1.0) return (a + 2.0) * ax * ax * ax - (a + 3.0) * ax * ax + 1.0;
    if (ax < 2.0)  return a * ax * ax * ax - 5.0 * a * ax * ax + 8.0 * a * ax - 4.0 * a;
    return 0.0;
}
__global__ void k_wmat(float* __restrict__ wm) {
    int t = threadIdx.x;          // 64 threads = 4 scales x 16 rows
    if (t >= 64) return;
    int sIdx = t >> 4;            // 0..3 -> S = 1,2,4,8
    int S = 1 << sIdx;
    int j = t & 15;
    const int offs[4] = {0, 16, 48, 112};
    int off = offs[sIdx];
    double row[8];
    for (int s = 0; s < 8; ++s) row[s] = 0.0;
    double scale = (double)S / 16.0;
    double x = (j + 0.5) * scale - 0.5;
    double x0 = floor(x);
    double tt = x - x0;
    for (int k = 0; k < 4; ++k) {
        int idx = (int)x0 - 1 + k;
        idx = idx < 0 ? 0 : (idx > S - 1 ? S - 1 : idx);
        row[idx] += cubic_d(tt + 1.0 - k);
    }
    for (int s = 0; s < S; ++s) wm[off + j * S + s] = (float)row[s];
}

// ---------------------------------------------------------------------------
// pack: r[n][c] = blockmean of f_rest ; thread-per-output (S=4,8,16)
__global__ void k_pack(const float* __restrict__ fr, float* __restrict__ rOut,
                       int S, int lgS) {
    int id = blockIdx.x * 256 + threadIdx.x;
    int total = 16 * S * S * 128;
    if (id >= total) return;
    int c = id & 127, n = id >> 7;
    int mask = S - 1;
    int tt = n & mask, ss = (n >> lgS) & mask, b = n >> (2 * lgS);
    int bs = 16 >> lgS;
    const float* base = fr + (size_t)(b * 128 + c) * 256 + (ss * bs) * 16 + tt * bs;
    float acc = 0.f;
    for (int jj = 0; jj < bs; ++jj)
        for (int ll = 0; ll < bs; ++ll)
            acc += base[jj * 16 + ll];
    rOut[id] = acc / (float)(bs * bs);
}

// wave-per-output variant for S=1,2 (large reduction windows)
__global__ void k_pack_wave(const float* __restrict__ fr, float* __restrict__ rOut,
                            int S, int lgS) {
    int gid = blockIdx.x * 256 + threadIdx.x;
    int wid = gid >> 6;
    int lane = threadIdx.x & 63;
    int total = 16 * S * S * 128;
    if (wid >= total) return;
    int c = wid & 127, n = wid >> 7;
    int mask = S - 1;
    int tt = n & mask, ss = (n >> lgS) & mask, b = n >> (2 * lgS);
    int lgbs = 4 - lgS;
    int bs = 1 << lgbs;
    int cnt = bs * bs;
    const float* base = fr + (size_t)(b * 128 + c) * 256 + (ss * bs) * 16 + tt * bs;
    float acc = 0.f;
    for (int e = lane; e < cnt; e += 64) {
        int jj = e >> lgbs, ll = e & (bs - 1);
        acc += base[jj * 16 + ll];
    }
    #pragma unroll
    for (int off = 32; off; off >>= 1) acc += __shfl_down(acc, off);
    if (lane == 0) rOut[wid] = acc / (float)cnt;
}

// ---------------------------------------------------------------------------
// MFMA argmin: score = esq[k] - 2 * dot(r,e), split-bf16 3-term contraction.
// Block: 256 thr = 4 waves x 32 rows (M=128). B-tile: 64 codes staged in LDS
// (XOR-swizzled 16B chunks, global_load_lds). Grid: (padN/128, KS).
__global__ __launch_bounds__(256)
void k_argmin_mfma(const ushortT* __restrict__ rext, const ushortT* __restrict__ embext,
                   const float* __restrict__ esq, int N, int kPerSplit,
                   float* __restrict__ pval, int* __restrict__ pidx) {
    __shared__ ushortT Btile[64 * 32 * 8];     // 64 codes x 32 chunks x 8 bf16 = 32 KB
    const int t = threadIdx.x;
    const int w = t >> 6;                      // wave 0..3
    const int lane = t & 63;
    const int ln = lane & 15;                  // row/code within 16-tile
    const int q  = lane >> 4;                  // quad 0..3
    const int KS = gridDim.y;
    const int k0beg = blockIdx.y * kPerSplit;
    const int rowW = blockIdx.x * 128 + w * 32;

    // A fragments: 2 row-subtiles x 8 chunks, resident in VGPRs
    short8 a[2][8];
    {
        const ushortT* r0 = rext + (size_t)(rowW + ln) * 256 + q * 8;
        const ushortT* r1 = rext + (size_t)(rowW + 16 + ln) * 256 + q * 8;
        #pragma unroll
        for (int sb = 0; sb < 8; ++sb) {
            a[0][sb] = *reinterpret_cast<const short8*>(r0 + sb * 32);
            a[1][sb] = *reinterpret_cast<const short8*>(r1 + sb * 32);
        }
    }

    float minv[2][4];
    int   mini[2][4];
    #pragma unroll
    for (int tt = 0; tt < 2; ++tt)
        #pragma unroll
        for (int rg = 0; rg < 4; ++rg) { minv[tt][rg] = 3.4e38f; mini[tt][rg] = 0; }

    for (int k0 = k0beg; k0 < k0beg + kPerSplit; k0 += 64) {
        __syncthreads();   // previous tile fully consumed
        // stage 64 codes x 512B, swizzled: LDS chunk F=(n,cs) <- global chunk
        // c' = (cs&~7)|((cs&7)^(n&7)) of code k0+n
        #pragma unroll
        for (int i = 0; i < 8; ++i) {
            int F = (i * 4 + w) * 64 + lane;          // 0..2047
            int n = F >> 5, cs = F & 31;
            int cp = (cs & ~7) | ((cs & 7) ^ (n & 7));
            const ushortT* src = embext + (size_t)(k0 + n) * 256 + cp * 8;
            __builtin_amdgcn_global_load_lds(
                (const __attribute__((address_space(1))) unsigned int*)src,
                (__attribute__((address_space(3))) unsigned int*)&Btile[(size_t)((i * 4 + w) * 64) * 8],
                16, 0, 0);
        }
        __syncthreads();   // staging visible (barrier drains vmcnt)

        #pragma unroll
        for (int sub = 0; sub < 4; ++sub) {
            int n = sub * 16 + ln;
            short8 bfr[8];
            #pragma unroll
            for (int sb = 0; sb < 8; ++sb) {
                int cp = q + 4 * sb;
                int cs = (cp & ~7) | ((cp & 7) ^ (n & 7));
                bfr[sb] = *reinterpret_cast<const short8*>(&Btile[(size_t)(n * 32 + cs) * 8]);
            }
            float4v acc0 = {0.f, 0.f, 0.f, 0.f};
            float4v acc1 = {0.f, 0.f, 0.f, 0.f};
            #pragma unroll
            for (int s = 0; s < 12; ++s) {
                int as = s < 8 ? s : s - 8;
                int bs = s < 4 ? s : s - 4;
                acc0 = __builtin_amdgcn_mfma_f32_16x16x32_bf16(a[0][as], bfr[bs], acc0, 0, 0, 0);
                acc1 = __builtin_amdgcn_mfma_f32_16x16x32_bf16(a[1][as], bfr[bs], acc1, 0, 0, 0);
            }
            int kc = k0 + sub * 16 + ln;
            float es = esq[kc];
            #pragma unroll
            for (int rg = 0; rg < 4; ++rg) {
                float sc0 = fmaf(-2.f, acc0[rg], es);
                if (sc0 < minv[0][rg]) { minv[0][rg] = sc0; mini[0][rg] = kc; }
                float sc1 = fmaf(-2.f, acc1[rg], es);
                if (sc1 < minv[1][rg]) { minv[1][rg] = sc1; mini[1][rg] = kc; }
            }
        }
    }

    // cross-lane min over the 16 codes held in ln (lanes differing in low 4 bits)
    #pragma unroll
    for (int tt = 0; tt < 2; ++tt)
        #pragma unroll
        for (int rg = 0; rg < 4; ++rg) {
            float v = minv[tt][rg]; int ix = mini[tt][rg];
            #pragma unroll
            for (int off = 1; off < 16; off <<= 1) {
                float ov = __shfl_xor(v, off);
                int   oi = __shfl_xor(ix, off);
                if (ov < v) { v = ov; ix = oi; }
            }
            minv[tt][rg] = v; mini[tt][rg] = ix;
        }
    if (ln == 0) {
        #pragma unroll
        for (int tt = 0; tt < 2; ++tt)
            #pragma unroll
            for (int rg = 0; rg < 4; ++rg) {
                int row = rowW + tt * 16 + q * 4 + rg;
                if (row < N) {
                    pval[(size_t)row * KS + blockIdx.y] = minv[tt][rg];
                    pidx[(size_t)row * KS + blockIdx.y] = mini[tt][rg];
                }
            }
    }
}

__global__ void k_argmin_reduce(const float* __restrict__ pval,
                                const int* __restrict__ pidx,
                                int N, int KS, int* __restrict__ idx_out) {
    int row = blockIdx.x * 256 + threadIdx.x;
    if (row >= N) return;
    float bv = pval[(size_t)row * KS];
    int bi = pidx[(size_t)row * KS];
    for (int ks = 1; ks < KS; ++ks) {
        float v = pval[(size_t)row * KS + ks];
        if (v < bv) { bv = v; bi = pidx[(size_t)row * KS + ks]; }
    }
    idx_out[row] = bi;
}

// ---------------------------------------------------------------------------
// bicubic upsample of gathered codes: block = one (b,c) 16x16 plane
__global__ void k_upsample(const float* __restrict__ emb, const int* __restrict__ idx,
                           const float* __restrict__ wm, int S, float* __restrict__ h_up) {
    const int bc = blockIdx.x;
    const int b = bc >> 7, c = bc & 127;
    const int t = threadIdx.x;
    const int j = t >> 4, l = t & 15;
    float acc = 0.f;
    for (int s = 0; s < S; ++s) {
        float wjv = wm[j * S + s];
        for (int tt = 0; tt < S; ++tt) {
            float wlv = wm[l * S + tt];
            int n = (b * S + s) * S + tt;
            acc += wjv * wlv * emb[(size_t)idx[n] * CDIM + c];
        }
    }
    h_up[(size_t)bc * 256 + t] = acc;
}

// scale 4: plain gather-transpose
__global__ void k_gather16(const float* __restrict__ emb, const int* __restrict__ idx,
                           float* __restrict__ h_up) {
    int id = blockIdx.x * 256 + threadIdx.x;
    int l = id & 15, j = (id >> 4) & 15, c = (id >> 8) & 127, b = id >> 15;
    int n = (b * 16 + j) * 16 + l;
    h_up[id] = emb[(size_t)idx[n] * CDIM + c];
}

// ---------------------------------------------------------------------------
// conv3x3 (SAME, zero pad) + 0.5 residual mix + f_hat/f_rest update + loss
__global__ __launch_bounds__(256)
void k_conv(const float* __restrict__ h_up, const float* __restrict__ w,
            const float* __restrict__ bias, const float* __restrict__ f_in,
            float* __restrict__ f_hat, float* __restrict__ f_rest,
            float* __restrict__ loss_acc) {
    __shared__ float tile[8][256];
    __shared__ float wl[576];          // 8 co x 8 ci x 9
    __shared__ float wsum[4];
    const int b   = blockIdx.x >> 4;
    const int co0 = (blockIdx.x & 15) * 8;
    const int t = threadIdx.x;
    const int col = t >> 5;            // co_local 0..7
    const int tid5 = t & 31;
    const int j0 = (tid5 >> 2) * 2;
    const int l0 = (tid5 & 3) * 4;
    const int co = co0 + col;
    const float* hb = h_up + (size_t)b * 32768;
    float acc[2][4] = {{0.f,0.f,0.f,0.f},{0.f,0.f,0.f,0.f}};

    for (int ci0 = 0; ci0 < 128; ci0 += 8) {
        __syncthreads();
        #pragma unroll
        for (int p = 0; p < 8; ++p) tile[p][t] = hb[(ci0 + p) * 256 + t];
        for (int i = t; i < 576; i += 256) {
            int cl = i / 72, rem = i % 72;
            int p = rem / 9, qq = rem % 9;
            wl[i] = w[((size_t)(co0 + cl) * 128 + (ci0 + p)) * 9 + qq];
        }
        __syncthreads();
        #pragma unroll
        for (int p = 0; p < 8; ++p) {
            float in[4][6];
            #pragma unroll
            for (int rr = 0; rr < 4; ++rr) {
                int jj = j0 - 1 + rr;
                #pragma unroll
                for (int cc = 0; cc < 6; ++cc) {
                    int ll = l0 - 1 + cc;
                    in[rr][cc] = (jj >= 0 && jj < 16 && ll >= 0 && ll < 16)
                                   ? tile[p][jj * 16 + ll] : 0.f;
                }
            }
            const float* wp = &wl[(col * 8 + p) * 9];
            #pragma unroll
            for (int dj = 0; dj < 3; ++dj)
                #pragma unroll
                for (int dl = 0; dl < 3; ++dl) {
                    float wv = wp[dj * 3 + dl];
                    #pragma unroll
                    for (int rr = 0; rr < 2; ++rr)
                        #pragma unroll
                        for (int cc = 0; cc < 4; ++cc)
                            acc[rr][cc] += wv * in[dj + rr][dl + cc];
                }
        }
    }

    float bsv = bias[co];
    float s = 0.f;
    #pragma unroll
    for (int rr = 0; rr < 2; ++rr) {
        #pragma unroll
        for (int cc = 0; cc < 4; ++cc) {
            int j = j0 + rr, l = l0 + cc;
            size_t gi = (size_t)(b * 128 + co) * 256 + j * 16 + l;
            float hv = h_up[gi];
            float outv = 0.5f * hv + 0.5f * (acc[rr][cc] + bsv);
            float fh = f_hat[gi] + outv;
            f_hat[gi] = fh;
            f_rest[gi] -= outv;
            float d = fh - f_in[gi];
            s += d * d;
        }
    }
    #pragma unroll
    for (int off = 32; off; off >>= 1) s += __shfl_down(s, off);
    if ((t & 63) == 0) wsum[t >> 6] = s;
    __syncthreads();
    if (t == 0)
        atomicAdd(loss_acc, (wsum[0] + wsum[1] + wsum[2] + wsum[3]) * LOSS_COEF);
}

// ---------------------------------------------------------------------------
__global__ void k_scatter(const int* __restrict__ idxb, float* __restrict__ counts) {
    int i = blockIdx.x * 256 + threadIdx.x;
    if (i < NTOT) atomicAdd(&counts[idxb[i]], 1.0f);
}

__global__ void k_final(const float* __restrict__ counts,
                        const float* __restrict__ loss_acc, float* __restrict__ out) {
    __shared__ float ws4[4];
    int t = threadIdx.x;
    float s = 0.f;
    for (int k = t; k < NCODE; k += 256) {
        float p = counts[k] * (1.0f / (float)NTOT);
        s += p * logf(p + 1e-10f);
    }
    #pragma unroll
    for (int off = 32; off; off >>= 1) s += __shfl_down(s, off);
    if ((t & 63) == 0) ws4[t >> 6] = s;
    __syncthreads();
    if (t == 0) {
        out[ELEMS]     = loss_acc[0];
        out[ELEMS + 1] = expf(-(ws4[0] + ws4[1] + ws4[2] + ws4[3]));
    }
}

// ---------------------------------------------------------------------------
extern "C" void kernel_launch(void* const* d_in, const int* in_sizes, int n_in,
                              void* d_out, int out_size, void* d_ws, size_t ws_size,
                              hipStream_t stream) {
    const float* f     = (const float*)d_in[0];
    const float* emb   = (const float*)d_in[1];
    const float* phi_w = (const float*)d_in[2];
    const float* phi_b = (const float*)d_in[3];
    float* out = (float*)d_out;

    float* wsf    = (float*)d_ws;
    float*   f_rest = wsf;                        // 524288
    float*   h_up   = wsf + 524288;               // 524288
    float*   rbuf   = wsf + 1048576;              // 524288
    float*   esq    = wsf + 1572864;              // 16384
    float*   wmat   = wsf + 1589248;              // 256
    float*   counts = wsf + 1589504;              // 16384
    float*   lossA  = wsf + 1605888;              // 64
    float*   pval   = wsf + 1605952;              // 65536
    int*     pidx   = (int*)(wsf + 1671488);      // 65536
    int*     idxb   = (int*)(wsf + 1737024);      // 8192
    ushortT* embext = (ushortT*)(wsf + 1745216);  // 16384*256 us = 2097152 floats
    ushortT* rext   = (ushortT*)(wsf + 3842368);  // 4096*256 us = 524288 floats
    // total ~ 4.37M floats = 17.5 MB

    k_init<<<2048, 256, 0, stream>>>(f, f_rest, out, counts, lossA);
    k_esq<<<64, 256, 0, stream>>>(emb, esq);
    k_embext<<<2048, 256, 0, stream>>>(emb, embext);
    k_wmat<<<1, 64, 0, stream>>>(wmat);

    const int Ss[5]     = {1, 2, 4, 8, 16};
    const int lgSs[5]   = {0, 1, 2, 3, 4};
    const int phiIdx[5] = {0, 1, 1, 2, 3};
    const int ksplit[5] = {256, 256, 128, 64, 16};
    const int wmOff[5]  = {0, 16, 48, 112, 0};
    int idxOff = 0;

    for (int si = 0; si < 5; ++si) {
        int S = Ss[si], lgS = lgSs[si];
        int N = 16 * S * S;
        int padN = (N + 127) & ~127;
        int total = N * 128;

        if (S <= 2)
            k_pack_wave<<<(total * 64 + 255) / 256, 256, 0, stream>>>(f_rest, rbuf, S, lgS);
        else
            k_pack<<<(total + 255) / 256, 256, 0, stream>>>(f_rest, rbuf, S, lgS);

        k_rext<<<(padN * 32 + 255) / 256, 256, 0, stream>>>(rbuf, rext, N, padN);

        int KS = ksplit[si];
        int kps = NCODE / KS;
        k_argmin_mfma<<<dim3(padN / 128, KS), 256, 0, stream>>>(rext, embext, esq,
                                                                N, kps, pval, pidx);
        k_argmin_reduce<<<(N + 255) / 256, 256, 0, stream>>>(pval, pidx, N, KS, idxb + idxOff);

        if (si < 4)
            k_upsample<<<2048, 256, 0, stream>>>(emb, idxb + idxOff, wmat + wmOff[si], S, h_up);
        else
            k_gather16<<<2048, 256, 0, stream>>>(emb, idxb + idxOff, h_up);

        int k = phiIdx[si];
        k_conv<<<256, 256, 0, stream>>>(h_up, phi_w + (size_t)k * 147456,
                                        phi_b + (size_t)k * 128, f, out, f_rest, lossA);
        idxOff += N;
    }

    k_scatter<<<(NTOT + 255) / 256, 256, 0, stream>>>(idxb, counts);
    k_final<<<1, 256, 0, stream>>>(counts, lossA, out);
}

// Round 3
// 465.147 us; speedup vs baseline: 3.3692x; 2.0033x over previous
//
#include <hip/hip_runtime.h>
#include <hip/hip_bf16.h>
#include <math.h>

// Problem constants
#define BATCH 16
#define CDIM  128
#define JDIM  16
#define LDIM  16
#define NCODE 16384
#define PLANE 256            // J*L
#define ELEMS 524288         // B*C*J*L
#define NTOT  5456           // 16+64+256+1024+4096
// loss coeff: 1.25 / (5 * 524288) == 2^-21
#define LOSS_COEF 4.76837158203125e-7f

typedef __attribute__((ext_vector_type(8))) short short8;
typedef __attribute__((ext_vector_type(4))) float float4v;
typedef unsigned short ushortT;

__device__ __forceinline__ ushortT f2bf(float x) {
    __hip_bfloat16 h = __float2bfloat16(x);
    return *reinterpret_cast<ushortT*>(&h);
}

// ---------------------------------------------------------------------------
// init: f_rest = f, f_hat(out) = 0, counts = 0, loss = 0
__global__ void k_init(const float* __restrict__ f, float* __restrict__ f_rest,
                       float* __restrict__ f_hat, float* __restrict__ counts,
                       float* __restrict__ loss_acc) {
    int i = blockIdx.x * 256 + threadIdx.x;
    if (i < ELEMS) { f_rest[i] = f[i]; f_hat[i] = 0.f; }
    if (i < NCODE) counts[i] = 0.f;
    if (i == 0) loss_acc[0] = 0.f;
}

// ---------------------------------------------------------------------------
// e_sq[k] = sum_c emb[k][c]^2
__global__ void k_esq(const float* __restrict__ emb, float* __restrict__ esq) {
    int k = blockIdx.x * 256 + threadIdx.x;
    if (k >= NCODE) return;
    const float4* e = reinterpret_cast<const float4*>(emb + (size_t)k * CDIM);
    float s = 0.f;
    #pragma unroll
    for (int q = 0; q < 32; ++q) {
        float4 v = e[q];
        s += v.x * v.x + v.y * v.y + v.z * v.z + v.w * v.w;
    }
    esq[k] = s;
}

// ---------------------------------------------------------------------------
// emb -> split-bf16 extended rows: [hi(128) | lo(128)] per code
__global__ void k_embext(const float* __restrict__ emb, ushortT* __restrict__ ee) {
    int id = blockIdx.x * 256 + threadIdx.x;   // 16384*32
    if (id >= NCODE * 32) return;
    int row = id >> 5, c4 = id & 31;
    float4 v = reinterpret_cast<const float4*>(emb + (size_t)row * CDIM)[c4];
    ushortT hi[4], lo[4];
    float xs[4] = {v.x, v.y, v.z, v.w};
    #pragma unroll
    for (int i = 0; i < 4; ++i) {
        hi[i] = f2bf(xs[i]);
        __hip_bfloat16 h = *reinterpret_cast<__hip_bfloat16*>(&hi[i]);
        lo[i] = f2bf(xs[i] - __bfloat162float(h));
    }
    ushortT* base = ee + (size_t)row * 256;
    *reinterpret_cast<ushort4*>(base + c4 * 4)       = make_ushort4(hi[0], hi[1], hi[2], hi[3]);
    *reinterpret_cast<ushort4*>(base + 128 + c4 * 4) = make_ushort4(lo[0], lo[1], lo[2], lo[3]);
}

// r (fp32 [N][128]) -> split-bf16 [padN][hi(128)|lo(128)], zero pad rows
__global__ void k_rext(const float* __restrict__ r, ushortT* __restrict__ re,
                       int N, int padN) {
    int id = blockIdx.x * 256 + threadIdx.x;   // padN*32
    if (id >= padN * 32) return;
    int row = id >> 5, c4 = id & 31;
    ushortT hi[4], lo[4];
    if (row < N) {
        float4 v = reinterpret_cast<const float4*>(r + (size_t)row * CDIM)[c4];
        float xs[4] = {v.x, v.y, v.z, v.w};
        #pragma unroll
        for (int i = 0; i < 4; ++i) {
            hi[i] = f2bf(xs[i]);
            __hip_bfloat16 h = *reinterpret_cast<__hip_bfloat16*>(&hi[i]);
            lo[i] = f2bf(xs[i] - __bfloat162float(h));
        }
    } else {
        #pragma unroll
        for (int i = 0; i < 4; ++i) { hi[i] = 0; lo[i] = 0; }
    }
    ushortT* base = re + (size_t)row * 256;
    *reinterpret_cast<ushort4*>(base + c4 * 4)       = make_ushort4(hi[0], hi[1], hi[2], hi[3]);
    *reinterpret_cast<ushort4*>(base + 128 + c4 * 4) = make_ushort4(lo[0], lo[1], lo[2], lo[3]);
}

// ---------------------------------------------------------------------------
// Wext[k4][co][kk], kk = (dj*3+dl)*128 + ci ; value = bf16(0.5*W + 0.5*I_center)
__global__ void k_wext(const float* __restrict__ w, ushortT* __restrict__ we) {
    int id = blockIdx.x * 256 + threadIdx.x;      // 4*128*1152
    if (id >= 4 * 128 * 1152) return;
    int k4 = id / 147456, rem = id % 147456;
    int co = rem / 1152, kk = rem % 1152;
    int off = kk >> 7, ci = kk & 127;
    float v = 0.5f * w[(((size_t)(k4 * 128 + co)) * 128 + ci) * 9 + off];
    if (ci == co && off == 4) v += 0.5f;
    we[id] = f2bf(v);
}

// ---------------------------------------------------------------------------
// bicubic interpolation matrices (align_corners=False, a=-0.75), double math
__device__ double cubic_d(double x) {
    const double a = -0.75;
    double ax = fabs(x);
    if (ax <= 1.0) return (a + 2.0) * ax * ax * ax - (a + 3.0) * ax * ax + 1.0;
    if (ax < 2.0)  return a * ax * ax * ax - 5.0 * a * ax * ax + 8.0 * a * ax - 4.0 * a;
    return 0.0;
}
__global__ void k_wmat(float* __restrict__ wm) {
    int t = threadIdx.x;          // 64 threads = 4 scales x 16 rows
    if (t >= 64) return;
    int sIdx = t >> 4;            // 0..3 -> S = 1,2,4,8
    int S = 1 << sIdx;
    int j = t & 15;
    const int offs[4] = {0, 16, 48, 112};
    int off = offs[sIdx];
    double row[8];
    for (int s = 0; s < 8; ++s) row[s] = 0.0;
    double scale = (double)S / 16.0;
    double x = (j + 0.5) * scale - 0.5;
    double x0 = floor(x);
    double tt = x - x0;
    for (int k = 0; k < 4; ++k) {
        int idx = (int)x0 - 1 + k;
        idx = idx < 0 ? 0 : (idx > S - 1 ? S - 1 : idx);
        row[idx] += cubic_d(tt + 1.0 - k);
    }
    for (int s = 0; s < S; ++s) wm[off + j * S + s] = (float)row[s];
}

// ---------------------------------------------------------------------------
// pack: r[n][c] = blockmean of f_rest ; thread-per-output (S=4,8,16)
__global__ void k_pack(const float* __restrict__ fr, float* __restrict__ rOut,
                       int S, int lgS) {
    int id = blockIdx.x * 256 + threadIdx.x;
    int total = 16 * S * S * 128;
    if (id >= total) return;
    int c = id & 127, n = id >> 7;
    int mask = S - 1;
    int tt = n & mask, ss = (n >> lgS) & mask, b = n >> (2 * lgS);
    int bs = 16 >> lgS;
    const float* base = fr + (size_t)(b * 128 + c) * 256 + (ss * bs) * 16 + tt * bs;
    float acc = 0.f;
    for (int jj = 0; jj < bs; ++jj)
        for (int ll = 0; ll < bs; ++ll)
            acc += base[jj * 16 + ll];
    rOut[id] = acc / (float)(bs * bs);
}

// wave-per-output variant for S=1,2 (large reduction windows)
__global__ void k_pack_wave(const float* __restrict__ fr, float* __restrict__ rOut,
                            int S, int lgS) {
    int gid = blockIdx.x * 256 + threadIdx.x;
    int wid = gid >> 6;
    int lane = threadIdx.x & 63;
    int total = 16 * S * S * 128;
    if (wid >= total) return;
    int c = wid & 127, n = wid >> 7;
    int mask = S - 1;
    int tt = n & mask, ss = (n >> lgS) & mask, b = n >> (2 * lgS);
    int lgbs = 4 - lgS;
    int bs = 1 << lgbs;
    int cnt = bs * bs;
    const float* base = fr + (size_t)(b * 128 + c) * 256 + (ss * bs) * 16 + tt * bs;
    float acc = 0.f;
    for (int e = lane; e < cnt; e += 64) {
        int jj = e >> lgbs, ll = e & (bs - 1);
        acc += base[jj * 16 + ll];
    }
    #pragma unroll
    for (int off = 32; off; off >>= 1) acc += __shfl_down(acc, off);
    if (lane == 0) rOut[wid] = acc / (float)cnt;
}

// ---------------------------------------------------------------------------
// MFMA argmin: score = esq[k] - 2 * dot(r,e), split-bf16 3-term contraction.
__global__ __launch_bounds__(256)
void k_argmin_mfma(const ushortT* __restrict__ rext, const ushortT* __restrict__ embext,
                   const float* __restrict__ esq, int N, int kPerSplit,
                   float* __restrict__ pval, int* __restrict__ pidx) {
    __shared__ ushortT Btile[64 * 32 * 8];     // 32 KB
    const int t = threadIdx.x;
    const int w = t >> 6;
    const int lane = t & 63;
    const int ln = lane & 15;
    const int q  = lane >> 4;
    const int KS = gridDim.y;
    const int k0beg = blockIdx.y * kPerSplit;
    const int rowW = blockIdx.x * 128 + w * 32;

    short8 a[2][8];
    {
        const ushortT* r0 = rext + (size_t)(rowW + ln) * 256 + q * 8;
        const ushortT* r1 = rext + (size_t)(rowW + 16 + ln) * 256 + q * 8;
        #pragma unroll
        for (int sb = 0; sb < 8; ++sb) {
            a[0][sb] = *reinterpret_cast<const short8*>(r0 + sb * 32);
            a[1][sb] = *reinterpret_cast<const short8*>(r1 + sb * 32);
        }
    }

    float minv[2][4];
    int   mini[2][4];
    #pragma unroll
    for (int tt = 0; tt < 2; ++tt)
        #pragma unroll
        for (int rg = 0; rg < 4; ++rg) { minv[tt][rg] = 3.4e38f; mini[tt][rg] = 0; }

    for (int k0 = k0beg; k0 < k0beg + kPerSplit; k0 += 64) {
        __syncthreads();
        #pragma unroll
        for (int i = 0; i < 8; ++i) {
            int F = (i * 4 + w) * 64 + lane;
            int n = F >> 5, cs = F & 31;
            int cp = (cs & ~7) | ((cs & 7) ^ (n & 7));
            const ushortT* src = embext + (size_t)(k0 + n) * 256 + cp * 8;
            __builtin_amdgcn_global_load_lds(
                (const __attribute__((address_space(1))) unsigned int*)src,
                (__attribute__((address_space(3))) unsigned int*)&Btile[(size_t)((i * 4 + w) * 64) * 8],
                16, 0, 0);
        }
        __syncthreads();

        #pragma unroll
        for (int sub = 0; sub < 4; ++sub) {
            int n = sub * 16 + ln;
            short8 bfr[8];
            #pragma unroll
            for (int sb = 0; sb < 8; ++sb) {
                int cp = q + 4 * sb;
                int cs = (cp & ~7) | ((cp & 7) ^ (n & 7));
                bfr[sb] = *reinterpret_cast<const short8*>(&Btile[(size_t)(n * 32 + cs) * 8]);
            }
            float4v acc0 = {0.f, 0.f, 0.f, 0.f};
            float4v acc1 = {0.f, 0.f, 0.f, 0.f};
            #pragma unroll
            for (int s = 0; s < 12; ++s) {
                int as = s < 8 ? s : s - 8;
                int bs = s < 4 ? s : s - 4;
                acc0 = __builtin_amdgcn_mfma_f32_16x16x32_bf16(a[0][as], bfr[bs], acc0, 0, 0, 0);
                acc1 = __builtin_amdgcn_mfma_f32_16x16x32_bf16(a[1][as], bfr[bs], acc1, 0, 0, 0);
            }
            int kc = k0 + sub * 16 + ln;
            float es = esq[kc];
            #pragma unroll
            for (int rg = 0; rg < 4; ++rg) {
                float sc0 = fmaf(-2.f, acc0[rg], es);
                if (sc0 < minv[0][rg]) { minv[0][rg] = sc0; mini[0][rg] = kc; }
                float sc1 = fmaf(-2.f, acc1[rg], es);
                if (sc1 < minv[1][rg]) { minv[1][rg] = sc1; mini[1][rg] = kc; }
            }
        }
    }

    #pragma unroll
    for (int tt = 0; tt < 2; ++tt)
        #pragma unroll
        for (int rg = 0; rg < 4; ++rg) {
            float v = minv[tt][rg]; int ix = mini[tt][rg];
            #pragma unroll
            for (int off = 1; off < 16; off <<= 1) {
                float ov = __shfl_xor(v, off);
                int   oi = __shfl_xor(ix, off);
                if (ov < v) { v = ov; ix = oi; }
            }
            minv[tt][rg] = v; mini[tt][rg] = ix;
        }
    if (ln == 0) {
        #pragma unroll
        for (int tt = 0; tt < 2; ++tt)
            #pragma unroll
            for (int rg = 0; rg < 4; ++rg) {
                int row = rowW + tt * 16 + q * 4 + rg;
                if (row < N) {
                    pval[(size_t)row * KS + blockIdx.y] = minv[tt][rg];
                    pidx[(size_t)row * KS + blockIdx.y] = mini[tt][rg];
                }
            }
    }
}

__global__ void k_argmin_reduce(const float* __restrict__ pval,
                                const int* __restrict__ pidx,
                                int N, int KS, int* __restrict__ idx_out) {
    int row = blockIdx.x * 256 + threadIdx.x;
    if (row >= N) return;
    float bv = pval[(size_t)row * KS];
    int bi = pidx[(size_t)row * KS];
    for (int ks = 1; ks < KS; ++ks) {
        float v = pval[(size_t)row * KS + ks];
        if (v < bv) { bv = v; bi = pidx[(size_t)row * KS + ks]; }
    }
    idx_out[row] = bi;
}

// ---------------------------------------------------------------------------
// h_bf layout: [b][j][l][chunk_phys][8] bf16, chunk_phys = (cs&8)|((cs&7)^(l&7))
// bicubic upsample -> h_bf ; block = (b*16+j), thread = l*16+cs
__global__ void k_upsample(const float* __restrict__ emb, const int* __restrict__ idx,
                           const float* __restrict__ wm, int S, ushortT* __restrict__ h_bf) {
    const int bj = blockIdx.x;
    const int b = bj >> 4, j = bj & 15;
    const int t = threadIdx.x;
    const int l = t >> 4, cs = t & 15;
    float acc[8];
    #pragma unroll
    for (int i = 0; i < 8; ++i) acc[i] = 0.f;
    for (int s = 0; s < S; ++s) {
        float wjv = wm[j * S + s];
        for (int tt = 0; tt < S; ++tt) {
            float wv = wjv * wm[l * S + tt];
            int n = (b * S + s) * S + tt;
            const float* er = emb + (size_t)idx[n] * CDIM + cs * 8;
            float4 e0 = *reinterpret_cast<const float4*>(er);
            float4 e1 = *reinterpret_cast<const float4*>(er + 4);
            acc[0] += wv * e0.x; acc[1] += wv * e0.y;
            acc[2] += wv * e0.z; acc[3] += wv * e0.w;
            acc[4] += wv * e1.x; acc[5] += wv * e1.y;
            acc[6] += wv * e1.z; acc[7] += wv * e1.w;
        }
    }
    int phys = (cs & 8) | ((cs & 7) ^ (l & 7));
    short8 o;
    #pragma unroll
    for (int i = 0; i < 8; ++i) o[i] = (short)f2bf(acc[i]);
    *reinterpret_cast<short8*>(&h_bf[((size_t)(b * 256 + j * 16 + l) * 16 + phys) * 8]) = o;
}

// scale 4: direct gather into h_bf
__global__ void k_gather16(const float* __restrict__ emb, const int* __restrict__ idx,
                           ushortT* __restrict__ h_bf) {
    int id = blockIdx.x * 256 + threadIdx.x;    // 65536
    int cs = id & 15, l = (id >> 4) & 15, j = (id >> 8) & 15, b = id >> 12;
    int n = (b * 16 + j) * 16 + l;
    const float* er = emb + (size_t)idx[n] * CDIM + cs * 8;
    float4 e0 = *reinterpret_cast<const float4*>(er);
    float4 e1 = *reinterpret_cast<const float4*>(er + 4);
    float v[8] = {e0.x, e0.y, e0.z, e0.w, e1.x, e1.y, e1.z, e1.w};
    int phys = (cs & 8) | ((cs & 7) ^ (l & 7));
    short8 o;
    #pragma unroll
    for (int i = 0; i < 8; ++i) o[i] = (short)f2bf(v[i]);
    *reinterpret_cast<short8*>(&h_bf[((size_t)(b * 256 + j * 16 + l) * 16 + phys) * 8]) = o;
}

// ---------------------------------------------------------------------------
// MFMA implicit-GEMM conv3x3 with folded residual: Out = conv(W',h) + 0.5*bias
// grid = 16 b x 8 two-row strips ; block 256 = 4 waves (each 32 co x 32 pos)
// A = im2col (M=pos), B = Wext (N=co). C: row=(q*4+reg)=l, col=ln=co_local.
__global__ __launch_bounds__(256)
void k_convmm(const ushortT* __restrict__ h_bf, const ushortT* __restrict__ wext,
              const float* __restrict__ bias, const float* __restrict__ f_in,
              float* __restrict__ f_hat, float* __restrict__ f_rest,
              float* __restrict__ loss_acc) {
    __shared__ __align__(16) ushortT Htile[4 * 16 * 128];   // 16 KB
    __shared__ float wsum[4];
    const int t = threadIdx.x;
    const int w = t >> 6, lane = t & 63;
    const int ln = lane & 15, q = lane >> 4;
    const int b  = blockIdx.x >> 3;
    const int jA = (blockIdx.x & 7) * 2;

    // stage rows jA-1..jA+2 (pre-swizzled in h_bf), zero-pad OOB rows
    #pragma unroll
    for (int sr = 0; sr < 4; ++sr) {
        int jin = jA - 1 + sr;
        if (jin >= 0 && jin < 16) {
            const ushortT* src = h_bf + (size_t)(b * 256 + jin * 16) * 128 + (w * 64 + lane) * 8;
            __builtin_amdgcn_global_load_lds(
                (const __attribute__((address_space(1))) unsigned int*)src,
                (__attribute__((address_space(3))) unsigned int*)&Htile[sr * 2048 + w * 512],
                16, 0, 0);
        } else {
            *reinterpret_cast<float4*>(&Htile[sr * 2048 + t * 8]) =
                make_float4(0.f, 0.f, 0.f, 0.f);
        }
    }
    __syncthreads();

    const int co0 = w * 32;
    const ushortT* wA = wext + (size_t)(co0 + ln) * 1152;
    float4v acc[2][2];
    #pragma unroll
    for (int sm = 0; sm < 2; ++sm)
        #pragma unroll
        for (int sn = 0; sn < 2; ++sn)
            acc[sm][sn] = (float4v){0.f, 0.f, 0.f, 0.f};

    const short8 zz = {0, 0, 0, 0, 0, 0, 0, 0};
    #pragma unroll 3
    for (int off = 0; off < 9; ++off) {
        const int dj = off / 3, dl = off % 3;
        int cIn = ln + dl - 1;
        int cCl = cIn < 0 ? 0 : (cIn > 15 ? 15 : cIn);
        bool oob = (cIn != cCl);
        int rb0 = (dj * 16 + cCl) * 128;
        #pragma unroll
        for (int g = 0; g < 4; ++g) {
            int csl = g * 4 + q;
            int phys = (csl & 8) | ((csl & 7) ^ (cCl & 7));
            short8 a0 = *reinterpret_cast<const short8*>(&Htile[rb0 + phys * 8]);
            short8 a1 = *reinterpret_cast<const short8*>(&Htile[rb0 + 2048 + phys * 8]);
            if (oob) { a0 = zz; a1 = zz; }
            const ushortT* wr = wA + (off * 4 + g) * 32 + q * 8;
            short8 b0 = *reinterpret_cast<const short8*>(wr);
            short8 b1 = *reinterpret_cast<const short8*>(wr + 16 * 1152);
            acc[0][0] = __builtin_amdgcn_mfma_f32_16x16x32_bf16(a0, b0, acc[0][0], 0, 0, 0);
            acc[0][1] = __builtin_amdgcn_mfma_f32_16x16x32_bf16(a0, b1, acc[0][1], 0, 0, 0);
            acc[1][0] = __builtin_amdgcn_mfma_f32_16x16x32_bf16(a1, b0, acc[1][0], 0, 0, 0);
            acc[1][1] = __builtin_amdgcn_mfma_f32_16x16x32_bf16(a1, b1, acc[1][1], 0, 0, 0);
        }
    }

    float s = 0.f;
    #pragma unroll
    for (int sm = 0; sm < 2; ++sm) {
        int j = jA + sm;
        #pragma unroll
        for (int sn = 0; sn < 2; ++sn) {
            int co = co0 + sn * 16 + ln;
            float bsv = 0.5f * bias[co];
            size_t gi = ((size_t)(b * 128 + co) * 16 + j) * 16 + q * 4;
            float4 fh = *reinterpret_cast<const float4*>(&f_hat[gi]);
            float4 fr = *reinterpret_cast<const float4*>(&f_rest[gi]);
            float4 fv = *reinterpret_cast<const float4*>(&f_in[gi]);
            float o0 = acc[sm][sn][0] + bsv, o1 = acc[sm][sn][1] + bsv;
            float o2 = acc[sm][sn][2] + bsv, o3 = acc[sm][sn][3] + bsv;
            fh.x += o0; fh.y += o1; fh.z += o2; fh.w += o3;
            fr.x -= o0; fr.y -= o1; fr.z -= o2; fr.w -= o3;
            *reinterpret_cast<float4*>(&f_hat[gi]) = fh;
            *reinterpret_cast<float4*>(&f_rest[gi]) = fr;
            float d0 = fh.x - fv.x, d1 = fh.y - fv.y;
            float d2 = fh.z - fv.z, d3 = fh.w - fv.w;
            s += d0 * d0 + d1 * d1 + d2 * d2 + d3 * d3;
        }
    }
    #pragma unroll
    for (int off = 32; off; off >>= 1) s += __shfl_down(s, off);
    if ((t & 63) == 0) wsum[t >> 6] = s;
    __syncthreads();
    if (t == 0)
        atomicAdd(loss_acc, (wsum[0] + wsum[1] + wsum[2] + wsum[3]) * LOSS_COEF);
}

// ---------------------------------------------------------------------------
__global__ void k_scatter(const int* __restrict__ idxb, float* __restrict__ counts) {
    int i = blockIdx.x * 256 + threadIdx.x;
    if (i < NTOT) atomicAdd(&counts[idxb[i]], 1.0f);
}

__global__ void k_final(const float* __restrict__ counts,
                        const float* __restrict__ loss_acc, float* __restrict__ out) {
    __shared__ float ws4[4];
    int t = threadIdx.x;
    float s = 0.f;
    for (int k = t; k < NCODE; k += 256) {
        float p = counts[k] * (1.0f / (float)NTOT);
        s += p * logf(p + 1e-10f);
    }
    #pragma unroll
    for (int off = 32; off; off >>= 1) s += __shfl_down(s, off);
    if ((t & 63) == 0) ws4[t >> 6] = s;
    __syncthreads();
    if (t == 0) {
        out[ELEMS]     = loss_acc[0];
        out[ELEMS + 1] = expf(-(ws4[0] + ws4[1] + ws4[2] + ws4[3]));
    }
}

// ---------------------------------------------------------------------------
extern "C" void kernel_launch(void* const* d_in, const int* in_sizes, int n_in,
                              void* d_out, int out_size, void* d_ws, size_t ws_size,
                              hipStream_t stream) {
    const float* f     = (const float*)d_in[0];
    const float* emb   = (const float*)d_in[1];
    const float* phi_w = (const float*)d_in[2];
    const float* phi_b = (const float*)d_in[3];
    float* out = (float*)d_out;

    float* wsf    = (float*)d_ws;
    float*   f_rest = wsf;                        // 524288
    ushortT* h_bf   = (ushortT*)(wsf + 524288);   // 524288 us = 262144 f
    float*   rbuf   = wsf + 786432;               // 524288
    float*   esq    = wsf + 1310720;              // 16384
    float*   wmat   = wsf + 1327104;              // 256
    float*   counts = wsf + 1327360;              // 16384
    float*   lossA  = wsf + 1343744;              // 64
    float*   pval   = wsf + 1343808;              // 65536
    int*     pidx   = (int*)(wsf + 1409344);      // 65536
    int*     idxb   = (int*)(wsf + 1474880);      // 8192
    ushortT* embext = (ushortT*)(wsf + 1483072);  // 4194304 us = 2097152 f
    ushortT* rext   = (ushortT*)(wsf + 3580224);  // 1048576 us = 524288 f
    ushortT* wext   = (ushortT*)(wsf + 4104512);  // 589824 us = 294912 f
    // total ~ 4.40M floats = 17.6 MB

    k_init<<<2048, 256, 0, stream>>>(f, f_rest, out, counts, lossA);
    k_esq<<<64, 256, 0, stream>>>(emb, esq);
    k_embext<<<2048, 256, 0, stream>>>(emb, embext);
    k_wext<<<2304, 256, 0, stream>>>(phi_w, wext);
    k_wmat<<<1, 64, 0, stream>>>(wmat);

    const int Ss[5]     = {1, 2, 4, 8, 16};
    const int lgSs[5]   = {0, 1, 2, 3, 4};
    const int phiIdx[5] = {0, 1, 1, 2, 3};
    const int ksplit[5] = {256, 256, 128, 64, 16};
    const int wmOff[5]  = {0, 16, 48, 112, 0};
    int idxOff = 0;

    for (int si = 0; si < 5; ++si) {
        int S = Ss[si], lgS = lgSs[si];
        int N = 16 * S * S;
        int padN = (N + 127) & ~127;
        int total = N * 128;

        if (S <= 2)
            k_pack_wave<<<(total * 64 + 255) / 256, 256, 0, stream>>>(f_rest, rbuf, S, lgS);
        else
            k_pack<<<(total + 255) / 256, 256, 0, stream>>>(f_rest, rbuf, S, lgS);

        k_rext<<<(padN * 32 + 255) / 256, 256, 0, stream>>>(rbuf, rext, N, padN);

        int KS = ksplit[si];
        int kps = NCODE / KS;
        k_argmin_mfma<<<dim3(padN / 128, KS), 256, 0, stream>>>(rext, embext, esq,
                                                                N, kps, pval, pidx);
        k_argmin_reduce<<<(N + 255) / 256, 256, 0, stream>>>(pval, pidx, N, KS, idxb + idxOff);

        if (si < 4)
            k_upsample<<<256, 256, 0, stream>>>(emb, idxb + idxOff, wmat + wmOff[si], S, h_bf);
        else
            k_gather16<<<256, 256, 0, stream>>>(emb, idxb + idxOff, h_bf);

        int k = phiIdx[si];
        k_convmm<<<128, 256, 0, stream>>>(h_bf, wext + (size_t)k * 147456,
                                          phi_b + (size_t)k * 128, f, out, f_rest, lossA);
        idxOff += N;
    }

    k_scatter<<<(NTOT + 255) / 256, 256, 0, stream>>>(idxb, counts);
    k_final<<<1, 256, 0, stream>>>(counts, lossA, out);
}

// Round 4
// 392.229 us; speedup vs baseline: 3.9956x; 1.1859x over previous
//
#include <hip/hip_runtime.h>
#include <hip/hip_bf16.h>
#include <math.h>

// Problem constants
#define BATCH 16
#define CDIM  128
#define NCODE 16384
#define ELEMS 524288         // B*C*J*L
#define NTOT  5456           // 16+64+256+1024+4096
#define WEXT_TOT 589824      // 4*128*1152
// loss coeff: 1.25 / (5 * 524288) == 2^-21
#define LOSS_COEF 4.76837158203125e-7f

typedef __attribute__((ext_vector_type(8))) short short8;
typedef __attribute__((ext_vector_type(4))) float float4v;
typedef unsigned short ushortT;
typedef unsigned long long u64;
typedef unsigned int u32;

__device__ __forceinline__ ushortT f2bf(float x) {
    __hip_bfloat16 h = __float2bfloat16(x);
    return *reinterpret_cast<ushortT*>(&h);
}
__device__ __forceinline__ float bf2f(ushortT b) {
    __hip_bfloat16 h = *reinterpret_cast<__hip_bfloat16*>(&b);
    return __bfloat162float(h);
}
// monotone float -> uint mapping (for lexicographic u64 atomicMin)
__device__ __forceinline__ u32 ford(float v) {
    u32 b = __float_as_uint(v);
    return b ^ ((u32)((int)b >> 31) | 0x80000000u);
}

// ---------------------------------------------------------------------------
// bicubic kernel (align_corners=False, a=-0.75), double math
__device__ double cubic_d(double x) {
    const double a = -0.75;
    double ax = fabs(x);
    if (ax <= 1.0) return (a + 2.0) * ax * ax * ax - (a + 3.0) * ax * ax + 1.0;
    if (ax < 2.0)  return a * ax * ax * ax - 5.0 * a * ax * ax + 8.0 * a * ax - 4.0 * a;
    return 0.0;
}

// ---------------------------------------------------------------------------
// prologue: f_rest=f, f_hat=0, esq, embext(split-bf16), wext(folded conv W), wmat, loss=0
__global__ __launch_bounds__(256)
void k_prologue(const float* __restrict__ f, const float* __restrict__ emb,
                const float* __restrict__ phi_w,
                float* __restrict__ f_rest, float* __restrict__ f_hat,
                float* __restrict__ esq, ushortT* __restrict__ embext,
                ushortT* __restrict__ wext, float* __restrict__ wmat,
                float* __restrict__ lossA) {
    const int t = threadIdx.x;
    const int id = blockIdx.x * 256 + t;

    if (id < ELEMS) {
        f_rest[id] = f[id];
        f_hat[id] = 0.f;
        // embext: row = id>>5, 4 channels per thread; esq via 32-lane segment reduce
        int row = id >> 5, c4 = id & 31;
        float4 v = reinterpret_cast<const float4*>(emb + (size_t)row * CDIM)[c4];
        float xs[4] = {v.x, v.y, v.z, v.w};
        ushortT hi[4], lo[4];
        float ss = 0.f;
        #pragma unroll
        for (int i = 0; i < 4; ++i) {
            hi[i] = f2bf(xs[i]);
            lo[i] = f2bf(xs[i] - bf2f(hi[i]));
            ss += xs[i] * xs[i];
        }
        ushortT* base = embext + (size_t)row * 256;
        *reinterpret_cast<ushort4*>(base + c4 * 4)       = make_ushort4(hi[0], hi[1], hi[2], hi[3]);
        *reinterpret_cast<ushort4*>(base + 128 + c4 * 4) = make_ushort4(lo[0], lo[1], lo[2], lo[3]);
        #pragma unroll
        for (int off = 16; off; off >>= 1) ss += __shfl_down(ss, off);
        if ((t & 31) == 0) esq[row] = ss;
    }
    if (id < WEXT_TOT) {
        int k4 = id / 147456, rem = id % 147456;
        int co = rem / 1152, kk = rem % 1152;
        int off = kk >> 7, ci = kk & 127;
        float v = 0.5f * phi_w[(((size_t)(k4 * 128 + co)) * 128 + ci) * 9 + off];
        if (ci == co && off == 4) v += 0.5f;
        wext[id] = f2bf(v);
    }
    if (blockIdx.x == 0 && t < 64) {
        int sIdx = t >> 4;            // S = 1,2,4,8
        int S = 1 << sIdx;
        int j = t & 15;
        const int offs[4] = {0, 16, 48, 112};
        double row[8];
        for (int s = 0; s < 8; ++s) row[s] = 0.0;
        double scale = (double)S / 16.0;
        double x = (j + 0.5) * scale - 0.5;
        double x0 = floor(x);
        double tt = x - x0;
        for (int k = 0; k < 4; ++k) {
            int idx = (int)x0 - 1 + k;
            idx = idx < 0 ? 0 : (idx > S - 1 ? S - 1 : idx);
            row[idx] += cubic_d(tt + 1.0 - k);
        }
        for (int s = 0; s < S; ++s) wmat[offs[sIdx] + j * S + s] = (float)row[s];
    }
    if (id == 0) lossA[0] = 0.f;
}

// ---------------------------------------------------------------------------
// fused pack+rext (S>=4): thread per (row, c4); also inits packed slab
__global__ __launch_bounds__(256)
void k_packext(const float* __restrict__ fr, ushortT* __restrict__ re,
               u64* __restrict__ packed, int N, int padN, int S, int lgS) {
    int id = blockIdx.x * 256 + threadIdx.x;
    if (id < N) packed[id] = ~0ull;
    if (id >= padN * 32) return;
    int row = id >> 5, c4 = id & 31;
    ushortT hi[4], lo[4];
    if (row < N) {
        int mask = S - 1;
        int tt = row & mask, ssi = (row >> lgS) & mask, b = row >> (2 * lgS);
        int bs = 16 >> lgS;
        float inv = 1.f / (float)(bs * bs);
        #pragma unroll
        for (int u = 0; u < 4; ++u) {
            int c = c4 * 4 + u;
            const float* base = fr + (size_t)(b * 128 + c) * 256 + (ssi * bs) * 16 + tt * bs;
            float acc = 0.f;
            for (int jj = 0; jj < bs; ++jj)
                for (int ll = 0; ll < bs; ++ll)
                    acc += base[jj * 16 + ll];
            float x = acc * inv;
            hi[u] = f2bf(x);
            lo[u] = f2bf(x - bf2f(hi[u]));
        }
    } else {
        #pragma unroll
        for (int u = 0; u < 4; ++u) { hi[u] = 0; lo[u] = 0; }
    }
    ushortT* base = re + (size_t)row * 256;
    *reinterpret_cast<ushort4*>(base + c4 * 4)       = make_ushort4(hi[0], hi[1], hi[2], hi[3]);
    *reinterpret_cast<ushort4*>(base + 128 + c4 * 4) = make_ushort4(lo[0], lo[1], lo[2], lo[3]);
}

// wave-per-(row,channel) variant for S<=2 (big windows)
__global__ __launch_bounds__(256)
void k_packext_wave(const float* __restrict__ fr, ushortT* __restrict__ re,
                    u64* __restrict__ packed, int N, int padN, int S, int lgS) {
    int gid = blockIdx.x * 256 + threadIdx.x;
    int wid = gid >> 6, lane = threadIdx.x & 63;
    if (wid >= padN * 128) return;
    int row = wid >> 7, c = wid & 127;
    float x = 0.f;
    if (row < N) {
        int mask = S - 1;
        int tt = row & mask, ssi = (row >> lgS) & mask, b = row >> (2 * lgS);
        int lgbs = 4 - lgS, bs = 1 << lgbs, cnt = bs * bs;
        const float* base = fr + (size_t)(b * 128 + c) * 256 + (ssi * bs) * 16 + tt * bs;
        float acc = 0.f;
        for (int e = lane; e < cnt; e += 64)
            acc += base[(e >> lgbs) * 16 + (e & (bs - 1))];
        #pragma unroll
        for (int off = 32; off; off >>= 1) acc += __shfl_down(acc, off);
        x = acc / (float)cnt;
    }
    if (lane == 0) {
        ushortT h = f2bf(x);
        re[(size_t)row * 256 + c] = h;
        re[(size_t)row * 256 + 128 + c] = f2bf(x - bf2f(h));
        if (c == 0 && row < N) packed[row] = ~0ull;
    }
}

// ---------------------------------------------------------------------------
// MFMA argmin, split-bf16 3-term; result via per-row u64 atomicMin (score,idx)
__global__ __launch_bounds__(256)
void k_argmin_mfma(const ushortT* __restrict__ rext, const ushortT* __restrict__ embext,
                   const float* __restrict__ esq, int N, int kPerSplit,
                   u64* __restrict__ packed) {
    __shared__ ushortT Btile[64 * 32 * 8];     // 32 KB
    const int t = threadIdx.x;
    const int w = t >> 6;
    const int lane = t & 63;
    const int ln = lane & 15;
    const int q  = lane >> 4;
    const int k0beg = blockIdx.y * kPerSplit;
    const int rowW = blockIdx.x * 128 + w * 32;

    short8 a[2][8];
    {
        const ushortT* r0 = rext + (size_t)(rowW + ln) * 256 + q * 8;
        const ushortT* r1 = rext + (size_t)(rowW + 16 + ln) * 256 + q * 8;
        #pragma unroll
        for (int sb = 0; sb < 8; ++sb) {
            a[0][sb] = *reinterpret_cast<const short8*>(r0 + sb * 32);
            a[1][sb] = *reinterpret_cast<const short8*>(r1 + sb * 32);
        }
    }

    float minv[2][4];
    int   mini[2][4];
    #pragma unroll
    for (int tt = 0; tt < 2; ++tt)
        #pragma unroll
        for (int rg = 0; rg < 4; ++rg) { minv[tt][rg] = 3.4e38f; mini[tt][rg] = 0; }

    for (int k0 = k0beg; k0 < k0beg + kPerSplit; k0 += 64) {
        __syncthreads();
        #pragma unroll
        for (int i = 0; i < 8; ++i) {
            int F = (i * 4 + w) * 64 + lane;
            int n = F >> 5, cs = F & 31;
            int cp = (cs & ~7) | ((cs & 7) ^ (n & 7));
            const ushortT* src = embext + (size_t)(k0 + n) * 256 + cp * 8;
            __builtin_amdgcn_global_load_lds(
                (const __attribute__((address_space(1))) unsigned int*)src,
                (__attribute__((address_space(3))) unsigned int*)&Btile[(size_t)((i * 4 + w) * 64) * 8],
                16, 0, 0);
        }
        __syncthreads();

        #pragma unroll
        for (int sub = 0; sub < 4; ++sub) {
            int n = sub * 16 + ln;
            short8 bfr[8];
            #pragma unroll
            for (int sb = 0; sb < 8; ++sb) {
                int cp = q + 4 * sb;
                int cs = (cp & ~7) | ((cp & 7) ^ (n & 7));
                bfr[sb] = *reinterpret_cast<const short8*>(&Btile[(size_t)(n * 32 + cs) * 8]);
            }
            float4v acc0 = {0.f, 0.f, 0.f, 0.f};
            float4v acc1 = {0.f, 0.f, 0.f, 0.f};
            #pragma unroll
            for (int s = 0; s < 12; ++s) {
                int as = s < 8 ? s : s - 8;
                int bs = s < 4 ? s : s - 4;
                acc0 = __builtin_amdgcn_mfma_f32_16x16x32_bf16(a[0][as], bfr[bs], acc0, 0, 0, 0);
                acc1 = __builtin_amdgcn_mfma_f32_16x16x32_bf16(a[1][as], bfr[bs], acc1, 0, 0, 0);
            }
            int kc = k0 + sub * 16 + ln;
            float es = esq[kc];
            #pragma unroll
            for (int rg = 0; rg < 4; ++rg) {
                float sc0 = fmaf(-2.f, acc0[rg], es);
                if (sc0 < minv[0][rg]) { minv[0][rg] = sc0; mini[0][rg] = kc; }
                float sc1 = fmaf(-2.f, acc1[rg], es);
                if (sc1 < minv[1][rg]) { minv[1][rg] = sc1; mini[1][rg] = kc; }
            }
        }
    }

    // min across the 16 code-lanes, then one atomicMin per row
    #pragma unroll
    for (int tt = 0; tt < 2; ++tt)
        #pragma unroll
        for (int rg = 0; rg < 4; ++rg) {
            float v = minv[tt][rg]; int ix = mini[tt][rg];
            #pragma unroll
            for (int off = 1; off < 16; off <<= 1) {
                float ov = __shfl_xor(v, off);
                int   oi = __shfl_xor(ix, off);
                if (ov < v || (ov == v && oi < ix)) { v = ov; ix = oi; }
            }
            if (ln == 0) {
                int row = rowW + tt * 16 + q * 4 + rg;
                if (row < N) {
                    u64 p = ((u64)ford(v) << 32) | (u32)ix;
                    atomicMin(&packed[row], p);
                }
            }
        }
}

// ---------------------------------------------------------------------------
// h_bf layout: [b][j][l][chunk_phys][8] bf16, chunk_phys = (cs&8)|((cs&7)^(l&7))
__global__ __launch_bounds__(256)
void k_upsample(const float* __restrict__ emb, const u64* __restrict__ packed,
                const float* __restrict__ wm, int S, ushortT* __restrict__ h_bf) {
    const int bj = blockIdx.x;
    const int b = bj >> 4, j = bj & 15;
    const int t = threadIdx.x;
    const int l = t >> 4, cs = t & 15;
    float acc[8];
    #pragma unroll
    for (int i = 0; i < 8; ++i) acc[i] = 0.f;
    for (int s = 0; s < S; ++s) {
        float wjv = wm[j * S + s];
        for (int tt = 0; tt < S; ++tt) {
            float wv = wjv * wm[l * S + tt];
            int n = (b * S + s) * S + tt;
            int idx = (int)(u32)(packed[n] & 0xFFFFFFFFull);
            const float* er = emb + (size_t)idx * CDIM + cs * 8;
            float4 e0 = *reinterpret_cast<const float4*>(er);
            float4 e1 = *reinterpret_cast<const float4*>(er + 4);
            acc[0] += wv * e0.x; acc[1] += wv * e0.y;
            acc[2] += wv * e0.z; acc[3] += wv * e0.w;
            acc[4] += wv * e1.x; acc[5] += wv * e1.y;
            acc[6] += wv * e1.z; acc[7] += wv * e1.w;
        }
    }
    int phys = (cs & 8) | ((cs & 7) ^ (l & 7));
    short8 o;
    #pragma unroll
    for (int i = 0; i < 8; ++i) o[i] = (short)f2bf(acc[i]);
    *reinterpret_cast<short8*>(&h_bf[((size_t)(b * 256 + j * 16 + l) * 16 + phys) * 8]) = o;
}

// scale 4: direct gather into h_bf
__global__ __launch_bounds__(256)
void k_gather16(const float* __restrict__ emb, const u64* __restrict__ packed,
                ushortT* __restrict__ h_bf) {
    int id = blockIdx.x * 256 + threadIdx.x;    // 65536
    int cs = id & 15, l = (id >> 4) & 15, j = (id >> 8) & 15, b = id >> 12;
    int n = (b * 16 + j) * 16 + l;
    int idx = (int)(u32)(packed[n] & 0xFFFFFFFFull);
    const float* er = emb + (size_t)idx * CDIM + cs * 8;
    float4 e0 = *reinterpret_cast<const float4*>(er);
    float4 e1 = *reinterpret_cast<const float4*>(er + 4);
    float v[8] = {e0.x, e0.y, e0.z, e0.w, e1.x, e1.y, e1.z, e1.w};
    int phys = (cs & 8) | ((cs & 7) ^ (l & 7));
    short8 o;
    #pragma unroll
    for (int i = 0; i < 8; ++i) o[i] = (short)f2bf(v[i]);
    *reinterpret_cast<short8*>(&h_bf[((size_t)(b * 256 + j * 16 + l) * 16 + phys) * 8]) = o;
}

// ---------------------------------------------------------------------------
// MFMA implicit-GEMM conv3x3 (folded residual). grid = (b,j,cohalf)=512 blocks,
// block = 128 thr = 2 waves; wave -> 32 co, one output row j (M=16 l-positions).
__global__ __launch_bounds__(128)
void k_convmm(const ushortT* __restrict__ h_bf, const ushortT* __restrict__ wext,
              const float* __restrict__ bias, const float* __restrict__ f_in,
              float* __restrict__ f_hat, float* __restrict__ f_rest,
              float* __restrict__ loss_acc) {
    __shared__ __align__(16) ushortT Htile[3 * 16 * 128];   // 12 KB: rows j-1..j+1
    __shared__ float wsum[2];
    const int t = threadIdx.x;
    const int w = t >> 6, lane = t & 63;
    const int ln = lane & 15, q = lane >> 4;
    const int ch = blockIdx.x & 1;
    const int j  = (blockIdx.x >> 1) & 15;
    const int b  = blockIdx.x >> 5;

    // stage 3 rows x 4 KB; per (issue,wave): 64 chunks of 16B, row-uniform
    #pragma unroll
    for (int i = 0; i < 6; ++i) {
        int Fb = i * 128 + w * 64;            // wave-uniform chunk base
        int sr = Fb >> 8;                     // 256 chunks per row
        int jin = j - 1 + sr;
        if (jin >= 0 && jin < 16) {
            int rc = (Fb & 255) + lane;
            const ushortT* src = h_bf + ((size_t)(b * 256 + jin * 16) * 16) * 8 + (size_t)rc * 8;
            __builtin_amdgcn_global_load_lds(
                (const __attribute__((address_space(1))) unsigned int*)src,
                (__attribute__((address_space(3))) unsigned int*)&Htile[(size_t)Fb * 8],
                16, 0, 0);
        } else {
            *reinterpret_cast<float4*>(&Htile[(size_t)(Fb + lane) * 8]) =
                make_float4(0.f, 0.f, 0.f, 0.f);
        }
    }
    __syncthreads();

    const int co0 = ch * 64 + w * 32;
    const ushortT* wA = wext + (size_t)(co0 + ln) * 1152;
    float4v acc[2] = {{0.f, 0.f, 0.f, 0.f}, {0.f, 0.f, 0.f, 0.f}};
    const short8 zz = {0, 0, 0, 0, 0, 0, 0, 0};

    #pragma unroll 3
    for (int off = 0; off < 9; ++off) {
        const int dj = off / 3, dl = off % 3;
        int cIn = ln + dl - 1;
        int cCl = cIn < 0 ? 0 : (cIn > 15 ? 15 : cIn);
        bool oob = (cIn != cCl);
        int rb = (dj * 16 + cCl) * 128;
        #pragma unroll
        for (int g = 0; g < 4; ++g) {
            int csl = g * 4 + q;
            int phys = (csl & 8) | ((csl & 7) ^ (cCl & 7));
            short8 av = *reinterpret_cast<const short8*>(&Htile[rb + phys * 8]);
            if (oob) av = zz;
            const ushortT* wr = wA + (off * 4 + g) * 32 + q * 8;
            short8 b0 = *reinterpret_cast<const short8*>(wr);
            short8 b1 = *reinterpret_cast<const short8*>(wr + 16 * 1152);
            acc[0] = __builtin_amdgcn_mfma_f32_16x16x32_bf16(av, b0, acc[0], 0, 0, 0);
            acc[1] = __builtin_amdgcn_mfma_f32_16x16x32_bf16(av, b1, acc[1], 0, 0, 0);
        }
    }

    float s = 0.f;
    #pragma unroll
    for (int sn = 0; sn < 2; ++sn) {
        int co = co0 + sn * 16 + ln;
        float bsv = 0.5f * bias[co];
        size_t gi = ((size_t)(b * 128 + co) * 16 + j) * 16 + q * 4;
        float4 fh = *reinterpret_cast<const float4*>(&f_hat[gi]);
        float4 fr = *reinterpret_cast<const float4*>(&f_rest[gi]);
        float4 fv = *reinterpret_cast<const float4*>(&f_in[gi]);
        float o0 = acc[sn][0] + bsv, o1 = acc[sn][1] + bsv;
        float o2 = acc[sn][2] + bsv, o3 = acc[sn][3] + bsv;
        fh.x += o0; fh.y += o1; fh.z += o2; fh.w += o3;
        fr.x -= o0; fr.y -= o1; fr.z -= o2; fr.w -= o3;
        *reinterpret_cast<float4*>(&f_hat[gi]) = fh;
        *reinterpret_cast<float4*>(&f_rest[gi]) = fr;
        float d0 = fh.x - fv.x, d1 = fh.y - fv.y;
        float d2 = fh.z - fv.z, d3 = fh.w - fv.w;
        s += d0 * d0 + d1 * d1 + d2 * d2 + d3 * d3;
    }
    #pragma unroll
    for (int off = 32; off; off >>= 1) s += __shfl_down(s, off);
    if (lane == 0) wsum[w] = s;
    __syncthreads();
    if (t == 0) atomicAdd(loss_acc, (wsum[0] + wsum[1]) * LOSS_COEF);
}

// ---------------------------------------------------------------------------
// fused histogram + perplexity + loss write (single block, LDS u16-pair counts)
__global__ __launch_bounds__(256)
void k_final(const u64* __restrict__ packed, const float* __restrict__ loss_acc,
             float* __restrict__ out) {
    __shared__ u32 cnt2[NCODE / 2];     // 32 KB, two u16 counts per word
    __shared__ float ws4[4];
    int t = threadIdx.x;
    for (int i = t; i < NCODE / 2; i += 256) cnt2[i] = 0;
    __syncthreads();
    for (int i = t; i < NTOT; i += 256) {
        int idx = (int)(u32)(packed[i] & 0xFFFFFFFFull);
        atomicAdd(&cnt2[idx >> 1], (idx & 1) ? 65536u : 1u);
    }
    __syncthreads();
    float s = 0.f;
    for (int k = t; k < NCODE; k += 256) {
        u32 c = cnt2[k >> 1];
        c = (k & 1) ? (c >> 16) : (c & 0xFFFFu);
        float p = (float)c * (1.0f / (float)NTOT);
        s += p * logf(p + 1e-10f);
    }
    #pragma unroll
    for (int off = 32; off; off >>= 1) s += __shfl_down(s, off);
    if ((t & 63) == 0) ws4[t >> 6] = s;
    __syncthreads();
    if (t == 0) {
        out[ELEMS]     = loss_acc[0];
        out[ELEMS + 1] = expf(-(ws4[0] + ws4[1] + ws4[2] + ws4[3]));
    }
}

// ---------------------------------------------------------------------------
extern "C" void kernel_launch(void* const* d_in, const int* in_sizes, int n_in,
                              void* d_out, int out_size, void* d_ws, size_t ws_size,
                              hipStream_t stream) {
    const float* f     = (const float*)d_in[0];
    const float* emb   = (const float*)d_in[1];
    const float* phi_w = (const float*)d_in[2];
    const float* phi_b = (const float*)d_in[3];
    float* out = (float*)d_out;

    float* wsf = (float*)d_ws;
    float*   f_rest = wsf;                        // 524288
    ushortT* h_bf   = (ushortT*)(wsf + 524288);   // 524288 us = 262144 f
    float*   esq    = wsf + 786432;               // 16384
    float*   wmat   = wsf + 802816;               // 256
    float*   lossA  = wsf + 803072;               // 64
    u64*     packed = (u64*)(wsf + 803136);       // 8192 u64 = 16384 f
    ushortT* embext = (ushortT*)(wsf + 819520);   // 4194304 us = 2097152 f
    ushortT* rext   = (ushortT*)(wsf + 2916672);  // 1048576 us = 524288 f
    ushortT* wext   = (ushortT*)(wsf + 3440960);  // 589824 us = 294912 f
    // total ~3.74M floats = 15.0 MB

    k_prologue<<<2304, 256, 0, stream>>>(f, emb, phi_w, f_rest, out, esq,
                                         embext, wext, wmat, lossA);

    const int Ss[5]     = {1, 2, 4, 8, 16};
    const int lgSs[5]   = {0, 1, 2, 3, 4};
    const int phiIdx[5] = {0, 1, 1, 2, 3};
    const int ksplit[5] = {256, 256, 256, 128, 32};
    const int wmOff[5]  = {0, 16, 48, 112, 0};
    const int pOff[5]   = {0, 16, 80, 336, 1360};

    for (int si = 0; si < 5; ++si) {
        int S = Ss[si], lgS = lgSs[si];
        int N = 16 * S * S;
        int padN = (N + 127) & ~127;
        u64* pk = packed + pOff[si];

        if (S <= 2)
            k_packext_wave<<<padN * 128 / 4, 256, 0, stream>>>(f_rest, rext, pk, N, padN, S, lgS);
        else
            k_packext<<<padN * 32 / 256, 256, 0, stream>>>(f_rest, rext, pk, N, padN, S, lgS);

        int KS = ksplit[si];
        k_argmin_mfma<<<dim3(padN / 128, KS), 256, 0, stream>>>(rext, embext, esq,
                                                                N, NCODE / KS, pk);

        if (si < 4)
            k_upsample<<<256, 256, 0, stream>>>(emb, pk, wmat + wmOff[si], S, h_bf);
        else
            k_gather16<<<256, 256, 0, stream>>>(emb, pk, h_bf);

        int k = phiIdx[si];
        k_convmm<<<512, 128, 0, stream>>>(h_bf, wext + (size_t)k * 147456,
                                          phi_b + (size_t)k * 128, f, out, f_rest, lossA);
    }

    k_final<<<1, 256, 0, stream>>>(packed, lossA, out);
}

// Round 5
// 358.425 us; speedup vs baseline: 4.3724x; 1.0943x over previous
//
#include <hip/hip_runtime.h>
#include <hip/hip_bf16.h>
#include <math.h>

// Problem constants
#define BATCH 16
#define CDIM  128
#define NCODE 16384
#define ELEMS 524288         // B*C*J*L
#define NTOT  5456           // 16+64+256+1024+4096
#define WEXT_TOT 589824      // 4*128*1152
// loss coeff: 1.25 / (5 * 524288) == 2^-21
#define LOSS_COEF 4.76837158203125e-7f

typedef __attribute__((ext_vector_type(8))) short short8;
typedef __attribute__((ext_vector_type(4))) float float4v;
typedef unsigned short ushortT;
typedef unsigned long long u64;
typedef unsigned int u32;

__device__ __forceinline__ ushortT f2bf(float x) {
    __hip_bfloat16 h = __float2bfloat16(x);
    return *reinterpret_cast<ushortT*>(&h);
}
__device__ __forceinline__ float bf2f(ushortT b) {
    __hip_bfloat16 h = *reinterpret_cast<__hip_bfloat16*>(&b);
    return __bfloat162float(h);
}
// monotone float -> uint mapping (for lexicographic u64 atomicMin)
__device__ __forceinline__ u32 ford(float v) {
    u32 b = __float_as_uint(v);
    return b ^ ((u32)((int)b >> 31) | 0x80000000u);
}

// ---------------------------------------------------------------------------
// bicubic kernel (align_corners=False, a=-0.75), double math
__device__ double cubic_d(double x) {
    const double a = -0.75;
    double ax = fabs(x);
    if (ax <= 1.0) return (a + 2.0) * ax * ax * ax - (a + 3.0) * ax * ax + 1.0;
    if (ax < 2.0)  return a * ax * ax * ax - 5.0 * a * ax * ax + 8.0 * a * ax - 4.0 * a;
    return 0.0;
}

// ---------------------------------------------------------------------------
// prologue: f_rest=f, f_hat=0, esq, embext(split-bf16), wext(folded conv W), wmat, loss=0
__global__ __launch_bounds__(256)
void k_prologue(const float* __restrict__ f, const float* __restrict__ emb,
                const float* __restrict__ phi_w,
                float* __restrict__ f_rest, float* __restrict__ f_hat,
                float* __restrict__ esq, ushortT* __restrict__ embext,
                ushortT* __restrict__ wext, float* __restrict__ wmat,
                float* __restrict__ lossA) {
    const int t = threadIdx.x;
    const int id = blockIdx.x * 256 + t;

    if (id < ELEMS) {
        f_rest[id] = f[id];
        f_hat[id] = 0.f;
        int row = id >> 5, c4 = id & 31;
        float4 v = reinterpret_cast<const float4*>(emb + (size_t)row * CDIM)[c4];
        float xs[4] = {v.x, v.y, v.z, v.w};
        ushortT hi[4], lo[4];
        float ss = 0.f;
        #pragma unroll
        for (int i = 0; i < 4; ++i) {
            hi[i] = f2bf(xs[i]);
            lo[i] = f2bf(xs[i] - bf2f(hi[i]));
            ss += xs[i] * xs[i];
        }
        ushortT* base = embext + (size_t)row * 256;
        *reinterpret_cast<ushort4*>(base + c4 * 4)       = make_ushort4(hi[0], hi[1], hi[2], hi[3]);
        *reinterpret_cast<ushort4*>(base + 128 + c4 * 4) = make_ushort4(lo[0], lo[1], lo[2], lo[3]);
        #pragma unroll
        for (int off = 16; off; off >>= 1) ss += __shfl_down(ss, off);
        if ((t & 31) == 0) esq[row] = ss;
    }
    if (id < WEXT_TOT) {
        int k4 = id / 147456, rem = id % 147456;
        int co = rem / 1152, kk = rem % 1152;
        int off = kk >> 7, ci = kk & 127;
        float v = 0.5f * phi_w[(((size_t)(k4 * 128 + co)) * 128 + ci) * 9 + off];
        if (ci == co && off == 4) v += 0.5f;
        wext[id] = f2bf(v);
    }
    if (blockIdx.x == 0 && t < 64) {
        int sIdx = t >> 4;            // S = 1,2,4,8
        int S = 1 << sIdx;
        int j = t & 15;
        const int offs[4] = {0, 16, 48, 112};
        double row[8];
        for (int s = 0; s < 8; ++s) row[s] = 0.0;
        double scale = (double)S / 16.0;
        double x = (j + 0.5) * scale - 0.5;
        double x0 = floor(x);
        double tt = x - x0;
        for (int k = 0; k < 4; ++k) {
            int idx = (int)x0 - 1 + k;
            idx = idx < 0 ? 0 : (idx > S - 1 ? S - 1 : idx);
            row[idx] += cubic_d(tt + 1.0 - k);
        }
        for (int s = 0; s < S; ++s) wmat[offs[sIdx] + j * S + s] = (float)row[s];
    }
    if (id == 0) lossA[0] = 0.f;
}

// ---------------------------------------------------------------------------
// fused pack+rext (S>=4): thread per (row, c4); also inits packed slab
__global__ __launch_bounds__(256)
void k_packext(const float* __restrict__ fr, ushortT* __restrict__ re,
               u64* __restrict__ packed, int N, int padN, int S, int lgS) {
    int id = blockIdx.x * 256 + threadIdx.x;
    if (id < N) packed[id] = ~0ull;
    if (id >= padN * 32) return;
    int row = id >> 5, c4 = id & 31;
    ushortT hi[4], lo[4];
    if (row < N) {
        int mask = S - 1;
        int tt = row & mask, ssi = (row >> lgS) & mask, b = row >> (2 * lgS);
        int bs = 16 >> lgS;
        float inv = 1.f / (float)(bs * bs);
        #pragma unroll
        for (int u = 0; u < 4; ++u) {
            int c = c4 * 4 + u;
            const float* base = fr + (size_t)(b * 128 + c) * 256 + (ssi * bs) * 16 + tt * bs;
            float acc = 0.f;
            for (int jj = 0; jj < bs; ++jj)
                for (int ll = 0; ll < bs; ++ll)
                    acc += base[jj * 16 + ll];
            float x = acc * inv;
            hi[u] = f2bf(x);
            lo[u] = f2bf(x - bf2f(hi[u]));
        }
    } else {
        #pragma unroll
        for (int u = 0; u < 4; ++u) { hi[u] = 0; lo[u] = 0; }
    }
    ushortT* base = re + (size_t)row * 256;
    *reinterpret_cast<ushort4*>(base + c4 * 4)       = make_ushort4(hi[0], hi[1], hi[2], hi[3]);
    *reinterpret_cast<ushort4*>(base + 128 + c4 * 4) = make_ushort4(lo[0], lo[1], lo[2], lo[3]);
}

// wave-per-(row,channel) variant for S<=2 (big windows)
__global__ __launch_bounds__(256)
void k_packext_wave(const float* __restrict__ fr, ushortT* __restrict__ re,
                    u64* __restrict__ packed, int N, int padN, int S, int lgS) {
    int gid = blockIdx.x * 256 + threadIdx.x;
    int wid = gid >> 6, lane = threadIdx.x & 63;
    if (wid >= padN * 128) return;
    int row = wid >> 7, c = wid & 127;
    float x = 0.f;
    if (row < N) {
        int mask = S - 1;
        int tt = row & mask, ssi = (row >> lgS) & mask, b = row >> (2 * lgS);
        int lgbs = 4 - lgS, bs = 1 << lgbs, cnt = bs * bs;
        const float* base = fr + (size_t)(b * 128 + c) * 256 + (ssi * bs) * 16 + tt * bs;
        float acc = 0.f;
        for (int e = lane; e < cnt; e += 64)
            acc += base[(e >> lgbs) * 16 + (e & (bs - 1))];
        #pragma unroll
        for (int off = 32; off; off >>= 1) acc += __shfl_down(acc, off);
        x = acc / (float)cnt;
    }
    if (lane == 0) {
        ushortT h = f2bf(x);
        re[(size_t)row * 256 + c] = h;
        re[(size_t)row * 256 + 128 + c] = f2bf(x - bf2f(h));
        if (c == 0 && row < N) packed[row] = ~0ull;
    }
}

// ---------------------------------------------------------------------------
// MFMA argmin, split-bf16 3-term; double-buffered B tile, ONE barrier/tile;
// result via per-row u64 atomicMin (score,idx)
__global__ __launch_bounds__(256)
void k_argmin_mfma(const ushortT* __restrict__ rext, const ushortT* __restrict__ embext,
                   const float* __restrict__ esq, int N, int kPerSplit,
                   u64* __restrict__ packed) {
    __shared__ ushortT Btile[2][64 * 32 * 8];     // 2 x 32 KB
    const int t = threadIdx.x;
    const int w = t >> 6;
    const int lane = t & 63;
    const int ln = lane & 15;
    const int q  = lane >> 4;
    const int k0beg = blockIdx.y * kPerSplit;
    const int rowW = blockIdx.x * 128 + w * 32;

    short8 a[2][8];
    {
        const ushortT* r0 = rext + (size_t)(rowW + ln) * 256 + q * 8;
        const ushortT* r1 = rext + (size_t)(rowW + 16 + ln) * 256 + q * 8;
        #pragma unroll
        for (int sb = 0; sb < 8; ++sb) {
            a[0][sb] = *reinterpret_cast<const short8*>(r0 + sb * 32);
            a[1][sb] = *reinterpret_cast<const short8*>(r1 + sb * 32);
        }
    }

    float minv[2][4];
    int   mini[2][4];
    #pragma unroll
    for (int tt = 0; tt < 2; ++tt)
        #pragma unroll
        for (int rg = 0; rg < 4; ++rg) { minv[tt][rg] = 3.4e38f; mini[tt][rg] = 0; }

    const int tiles = kPerSplit >> 6;

    // prologue stage into buffer 0
    #pragma unroll
    for (int i = 0; i < 8; ++i) {
        int F = (i * 4 + w) * 64 + lane;
        int n = F >> 5, cs = F & 31;
        int cp = (cs & ~7) | ((cs & 7) ^ (n & 7));
        const ushortT* src = embext + (size_t)(k0beg + n) * 256 + cp * 8;
        __builtin_amdgcn_global_load_lds(
            (const __attribute__((address_space(1))) unsigned int*)src,
            (__attribute__((address_space(3))) unsigned int*)&Btile[0][(size_t)((i * 4 + w) * 64) * 8],
            16, 0, 0);
    }

    for (int it = 0; it < tiles; ++it) {
        __syncthreads();   // drains prev stage (vmcnt) + prev compute's lds reads
        if (it + 1 < tiles) {
            int k1 = k0beg + (it + 1) * 64;
            int bu = (it + 1) & 1;
            #pragma unroll
            for (int i = 0; i < 8; ++i) {
                int F = (i * 4 + w) * 64 + lane;
                int n = F >> 5, cs = F & 31;
                int cp = (cs & ~7) | ((cs & 7) ^ (n & 7));
                const ushortT* src = embext + (size_t)(k1 + n) * 256 + cp * 8;
                __builtin_amdgcn_global_load_lds(
                    (const __attribute__((address_space(1))) unsigned int*)src,
                    (__attribute__((address_space(3))) unsigned int*)&Btile[bu][(size_t)((i * 4 + w) * 64) * 8],
                    16, 0, 0);
            }
        }
        const ushortT* Bt = Btile[it & 1];
        const int k0 = k0beg + it * 64;

        #pragma unroll
        for (int sub = 0; sub < 4; ++sub) {
            int n = sub * 16 + ln;
            short8 bfr[8];
            #pragma unroll
            for (int sb = 0; sb < 8; ++sb) {
                int cp = q + 4 * sb;
                int cs = (cp & ~7) | ((cp & 7) ^ (n & 7));
                bfr[sb] = *reinterpret_cast<const short8*>(&Bt[(size_t)(n * 32 + cs) * 8]);
            }
            float4v acc0 = {0.f, 0.f, 0.f, 0.f};
            float4v acc1 = {0.f, 0.f, 0.f, 0.f};
            #pragma unroll
            for (int s = 0; s < 12; ++s) {
                int as = s < 8 ? s : s - 8;
                int bs = s < 4 ? s : s - 4;
                acc0 = __builtin_amdgcn_mfma_f32_16x16x32_bf16(a[0][as], bfr[bs], acc0, 0, 0, 0);
                acc1 = __builtin_amdgcn_mfma_f32_16x16x32_bf16(a[1][as], bfr[bs], acc1, 0, 0, 0);
            }
            int kc = k0 + sub * 16 + ln;
            float es = esq[kc];
            #pragma unroll
            for (int rg = 0; rg < 4; ++rg) {
                float sc0 = fmaf(-2.f, acc0[rg], es);
                if (sc0 < minv[0][rg]) { minv[0][rg] = sc0; mini[0][rg] = kc; }
                float sc1 = fmaf(-2.f, acc1[rg], es);
                if (sc1 < minv[1][rg]) { minv[1][rg] = sc1; mini[1][rg] = kc; }
            }
        }
    }

    // min across the 16 code-lanes, then one atomicMin per row
    #pragma unroll
    for (int tt = 0; tt < 2; ++tt)
        #pragma unroll
        for (int rg = 0; rg < 4; ++rg) {
            float v = minv[tt][rg]; int ix = mini[tt][rg];
            #pragma unroll
            for (int off = 1; off < 16; off <<= 1) {
                float ov = __shfl_xor(v, off);
                int   oi = __shfl_xor(ix, off);
                if (ov < v || (ov == v && oi < ix)) { v = ov; ix = oi; }
            }
            if (ln == 0) {
                int row = rowW + tt * 16 + q * 4 + rg;
                if (row < N) {
                    u64 p = ((u64)ford(v) << 32) | (u32)ix;
                    atomicMin(&packed[row], p);
                }
            }
        }
}

// ---------------------------------------------------------------------------
// Fused upsample/gather + MFMA conv3x3 (folded residual) + f_hat/f_rest/loss.
// grid = (b,j) = 256 blocks; 256 thr = 4 waves, each 32 co (128 total).
// Phase 1: threads (l, c8) compute h rows j-1..j+1 (bicubic from packed idx,
//          or direct gather at last scale) -> swizzled bf16 Htile.
// Phase 2: implicit-GEMM conv identical to round-4 k_convmm.
__global__ __launch_bounds__(256)
void k_upconv(const float* __restrict__ emb, const u64* __restrict__ packed,
              const float* __restrict__ wm, int S, int lastScale,
              const ushortT* __restrict__ wext, const float* __restrict__ bias,
              const float* __restrict__ f_in, float* __restrict__ f_hat,
              float* __restrict__ f_rest, float* __restrict__ loss_acc) {
    __shared__ __align__(16) ushortT Htile[3 * 16 * 128];   // 12 KB
    __shared__ float wsum[4];
    const int t = threadIdx.x;
    const int b = blockIdx.x >> 4;
    const int j = blockIdx.x & 15;

    {   // ---- upsample phase: thread = (l, c8) ----
        const int l = t >> 4, c8 = t & 15;
        const int phys = (c8 & 8) | ((c8 & 7) ^ (l & 7));
        #pragma unroll
        for (int r = 0; r < 3; ++r) {
            int jin = j - 1 + r;
            float acc[8] = {0.f, 0.f, 0.f, 0.f, 0.f, 0.f, 0.f, 0.f};
            if (jin >= 0 && jin < 16) {
                if (lastScale) {
                    int idx = (int)(u32)(packed[(b * 16 + jin) * 16 + l] & 0xFFFFFFFFull);
                    const float* er = emb + (size_t)idx * CDIM + c8 * 8;
                    float4 e0 = *reinterpret_cast<const float4*>(er);
                    float4 e1 = *reinterpret_cast<const float4*>(er + 4);
                    acc[0] = e0.x; acc[1] = e0.y; acc[2] = e0.z; acc[3] = e0.w;
                    acc[4] = e1.x; acc[5] = e1.y; acc[6] = e1.z; acc[7] = e1.w;
                } else {
                    for (int s = 0; s < S; ++s) {
                        float wjv = wm[jin * S + s];
                        for (int tt2 = 0; tt2 < S; ++tt2) {
                            float wv = wjv * wm[l * S + tt2];
                            int idx = (int)(u32)(packed[(b * S + s) * S + tt2] & 0xFFFFFFFFull);
                            const float* er = emb + (size_t)idx * CDIM + c8 * 8;
                            float4 e0 = *reinterpret_cast<const float4*>(er);
                            float4 e1 = *reinterpret_cast<const float4*>(er + 4);
                            acc[0] += wv * e0.x; acc[1] += wv * e0.y;
                            acc[2] += wv * e0.z; acc[3] += wv * e0.w;
                            acc[4] += wv * e1.x; acc[5] += wv * e1.y;
                            acc[6] += wv * e1.z; acc[7] += wv * e1.w;
                        }
                    }
                }
            }
            short8 o;
            #pragma unroll
            for (int i = 0; i < 8; ++i) o[i] = (short)f2bf(acc[i]);
            *reinterpret_cast<short8*>(&Htile[((size_t)(r * 16 + l) * 16 + phys) * 8]) = o;
        }
    }
    __syncthreads();

    // ---- conv phase ----
    const int w = t >> 6, lane = t & 63;
    const int ln = lane & 15, q = lane >> 4;
    const int co0 = w * 32;
    const ushortT* wA = wext + (size_t)(co0 + ln) * 1152;
    float4v acc2[2] = {{0.f, 0.f, 0.f, 0.f}, {0.f, 0.f, 0.f, 0.f}};
    const short8 zz = {0, 0, 0, 0, 0, 0, 0, 0};

    #pragma unroll 3
    for (int off = 0; off < 9; ++off) {
        const int dj = off / 3, dl = off % 3;
        int cIn = ln + dl - 1;
        int cCl = cIn < 0 ? 0 : (cIn > 15 ? 15 : cIn);
        bool oob = (cIn != cCl);
        int rb = (dj * 16 + cCl) * 128;
        #pragma unroll
        for (int g = 0; g < 4; ++g) {
            int csl = g * 4 + q;
            int phys = (csl & 8) | ((csl & 7) ^ (cCl & 7));
            short8 av = *reinterpret_cast<const short8*>(&Htile[rb + phys * 8]);
            if (oob) av = zz;
            const ushortT* wr = wA + (off * 4 + g) * 32 + q * 8;
            short8 b0 = *reinterpret_cast<const short8*>(wr);
            short8 b1 = *reinterpret_cast<const short8*>(wr + 16 * 1152);
            acc2[0] = __builtin_amdgcn_mfma_f32_16x16x32_bf16(av, b0, acc2[0], 0, 0, 0);
            acc2[1] = __builtin_amdgcn_mfma_f32_16x16x32_bf16(av, b1, acc2[1], 0, 0, 0);
        }
    }

    float s = 0.f;
    #pragma unroll
    for (int sn = 0; sn < 2; ++sn) {
        int co = co0 + sn * 16 + ln;
        float bsv = 0.5f * bias[co];
        size_t gi = ((size_t)(b * 128 + co) * 16 + j) * 16 + q * 4;
        float4 fh = *reinterpret_cast<const float4*>(&f_hat[gi]);
        float4 fr = *reinterpret_cast<const float4*>(&f_rest[gi]);
        float4 fv = *reinterpret_cast<const float4*>(&f_in[gi]);
        float o0 = acc2[sn][0] + bsv, o1 = acc2[sn][1] + bsv;
        float o2 = acc2[sn][2] + bsv, o3 = acc2[sn][3] + bsv;
        fh.x += o0; fh.y += o1; fh.z += o2; fh.w += o3;
        fr.x -= o0; fr.y -= o1; fr.z -= o2; fr.w -= o3;
        *reinterpret_cast<float4*>(&f_hat[gi]) = fh;
        *reinterpret_cast<float4*>(&f_rest[gi]) = fr;
        float d0 = fh.x - fv.x, d1 = fh.y - fv.y;
        float d2 = fh.z - fv.z, d3 = fh.w - fv.w;
        s += d0 * d0 + d1 * d1 + d2 * d2 + d3 * d3;
    }
    #pragma unroll
    for (int off = 32; off; off >>= 1) s += __shfl_down(s, off);
    if (lane == 0) wsum[w] = s;
    __syncthreads();
    if (t == 0)
        atomicAdd(loss_acc, (wsum[0] + wsum[1] + wsum[2] + wsum[3]) * LOSS_COEF);
}

// ---------------------------------------------------------------------------
// fused histogram + perplexity + loss write (single block, LDS u16-pair counts)
__global__ __launch_bounds__(256)
void k_final(const u64* __restrict__ packed, const float* __restrict__ loss_acc,
             float* __restrict__ out) {
    __shared__ u32 cnt2[NCODE / 2];     // 32 KB, two u16 counts per word
    __shared__ float ws4[4];
    int t = threadIdx.x;
    for (int i = t; i < NCODE / 2; i += 256) cnt2[i] = 0;
    __syncthreads();
    for (int i = t; i < NTOT; i += 256) {
        int idx = (int)(u32)(packed[i] & 0xFFFFFFFFull);
        atomicAdd(&cnt2[idx >> 1], (idx & 1) ? 65536u : 1u);
    }
    __syncthreads();
    float s = 0.f;
    for (int k = t; k < NCODE; k += 256) {
        u32 c = cnt2[k >> 1];
        c = (k & 1) ? (c >> 16) : (c & 0xFFFFu);
        float p = (float)c * (1.0f / (float)NTOT);
        s += p * logf(p + 1e-10f);
    }
    #pragma unroll
    for (int off = 32; off; off >>= 1) s += __shfl_down(s, off);
    if ((t & 63) == 0) ws4[t >> 6] = s;
    __syncthreads();
    if (t == 0) {
        out[ELEMS]     = loss_acc[0];
        out[ELEMS + 1] = expf(-(ws4[0] + ws4[1] + ws4[2] + ws4[3]));
    }
}

// ---------------------------------------------------------------------------
extern "C" void kernel_launch(void* const* d_in, const int* in_sizes, int n_in,
                              void* d_out, int out_size, void* d_ws, size_t ws_size,
                              hipStream_t stream) {
    const float* f     = (const float*)d_in[0];
    const float* emb   = (const float*)d_in[1];
    const float* phi_w = (const float*)d_in[2];
    const float* phi_b = (const float*)d_in[3];
    float* out = (float*)d_out;

    float* wsf = (float*)d_ws;
    float*   f_rest = wsf;                        // 524288
    float*   esq    = wsf + 524288;               // 16384
    float*   wmat   = wsf + 540672;               // 256
    float*   lossA  = wsf + 540928;               // 64
    u64*     packed = (u64*)(wsf + 540992);       // 8192 u64 = 16384 f
    ushortT* embext = (ushortT*)(wsf + 557376);   // 4194304 us = 2097152 f
    ushortT* rext   = (ushortT*)(wsf + 2654528);  // 1048576 us = 524288 f
    ushortT* wext   = (ushortT*)(wsf + 3178816);  // 589824 us = 294912 f
    // total ~3.47M floats = 13.9 MB

    k_prologue<<<2304, 256, 0, stream>>>(f, emb, phi_w, f_rest, out, esq,
                                         embext, wext, wmat, lossA);

    const int Ss[5]     = {1, 2, 4, 8, 16};
    const int lgSs[5]   = {0, 1, 2, 3, 4};
    const int phiIdx[5] = {0, 1, 1, 2, 3};
    const int ksplit[5] = {256, 256, 128, 64, 16};
    const int wmOff[5]  = {0, 16, 48, 112, 0};
    const int pOff[5]   = {0, 16, 80, 336, 1360};

    for (int si = 0; si < 5; ++si) {
        int S = Ss[si], lgS = lgSs[si];
        int N = 16 * S * S;
        int padN = (N + 127) & ~127;
        u64* pk = packed + pOff[si];

        if (S <= 2)
            k_packext_wave<<<padN * 128 / 4, 256, 0, stream>>>(f_rest, rext, pk, N, padN, S, lgS);
        else
            k_packext<<<padN * 32 / 256, 256, 0, stream>>>(f_rest, rext, pk, N, padN, S, lgS);

        int KS = ksplit[si];
        k_argmin_mfma<<<dim3(padN / 128, KS), 256, 0, stream>>>(rext, embext, esq,
                                                                N, NCODE / KS, pk);

        int k = phiIdx[si];
        k_upconv<<<256, 256, 0, stream>>>(emb, pk, wmat + wmOff[si], S, si == 4 ? 1 : 0,
                                          wext + (size_t)k * 147456,
                                          phi_b + (size_t)k * 128, f, out, f_rest, lossA);
    }

    k_final<<<1, 256, 0, stream>>>(packed, lossA, out);
}